// Round 2
// baseline (572.993 us; speedup 1.0000x reference)
//
#include <hip/hip_runtime.h>
#include <hip/hip_bf16.h>
#include <stdint.h>

// Problem: B=1, N=M=256, D=256, E=128, H=4, HD=32, P=64
typedef __hip_bfloat16 bf16;

__device__ __forceinline__ float b2f(bf16 v) { return __bfloat162float(v); }
__device__ __forceinline__ float u2f_lo(uint32_t u) { union { uint32_t u; float f; } c; c.u = u << 16;         return c.f; }
__device__ __forceinline__ float u2f_hi(uint32_t u) { union { uint32_t u; float f; } c; c.u = u & 0xffff0000u; return c.f; }

// generic input loaders: flag-driven (inputs may be bf16 or f32)
__device__ __forceinline__ float ldE(const void* p, int i, bool f32) {
    return f32 ? ((const float*)p)[i] : b2f(((const bf16*)p)[i]);
}
__device__ __forceinline__ void ld8(const void* p, int base, bool f32, float* o) {
    if (f32) {
        const float4* q = (const float4*)((const float*)p + base);
        float4 a = q[0], b = q[1];
        o[0]=a.x; o[1]=a.y; o[2]=a.z; o[3]=a.w; o[4]=b.x; o[5]=b.y; o[6]=b.z; o[7]=b.w;
    } else {
        uint4 u = *((const uint4*)((const bf16*)p + base));
        o[0]=u2f_lo(u.x); o[1]=u2f_hi(u.x); o[2]=u2f_lo(u.y); o[3]=u2f_hi(u.y);
        o[4]=u2f_lo(u.z); o[5]=u2f_hi(u.z); o[6]=u2f_lo(u.w); o[7]=u2f_hi(u.w);
    }
}

// workspace layout (float offsets); ws[0] holds the dtype flag (int, 1 = f32 inputs)
#define OFF_U     8         // [256][64]  u = x_pos@k_w1^T + k_b1
#define OFF_W     16392     // [256][64]  w = y_pos@k_w1^T
#define OFF_WPHI  32776     // [128][64]  phi_pe @ k_w2
#define OFF_WG    40968     // [128][64]  g_pe @ k_w2
#define OFF_PHIB  49160     // [128]      phi_pe @ k_b2
#define OFF_GB    49288     // [128]      g_pe @ k_b2
#define OFF_QS    49416     // [256][128] q (scaled)
#define OFF_AX    82184     // [256][128] x @ phi_msg^T
#define OFF_AYP   114952    // [256][128] y @ phi_msg^T - phib
#define OFF_GX    147720    // [256][128] x @ g_msg^T
#define OFF_GYP   180488    // [256][128] y @ g_msg^T - gb
#define OFF_PO    213256    // [64 c][4 h][256 q][32]  partial sum(exp*v)
#define OFF_PL    2310408   // [64 c][4 h][256 q]      partial sum(exp)
// total 2375944 floats = 9.5 MB

// ---------------------------------------------------------------- dtype detect
__global__ void k_detect(const void* __restrict__ x, int* __restrict__ flag) {
    __shared__ int cnt;
    if (threadIdx.x == 0) cnt = 0;
    __syncthreads();
    const uint32_t* w = (const uint32_t*)x;
    int c = 0;
    for (int i = threadIdx.x; i < 1024; i += 256) {
        uint32_t e = (w[i] >> 7) & 0xFFu;   // bf16 low-half exponent field / f32 mantissa bits
        c += (e >= 96 && e <= 160) ? 1 : 0;
    }
    atomicAdd(&cnt, c);
    __syncthreads();
    if (threadIdx.x == 0) flag[0] = (cnt >= 640) ? 0 : 1;   // bf16 ~1024 hits, f32 ~260
}

// ---------------------------------------------------------------- K0: tiny precomputes
__global__ void __launch_bounds__(256) k0_prep(
    const void* __restrict__ xpos, const void* __restrict__ ypos,
    const void* __restrict__ kw1,  const void* __restrict__ kb1,
    const void* __restrict__ kw2,  const void* __restrict__ kb2,
    const void* __restrict__ phiw, const void* __restrict__ gw,
    float* __restrict__ ws)
{
    const bool f32 = ((const int*)ws)[0] != 0;
    int id = blockIdx.x * 256 + threadIdx.x;
    if (id < 16384) {                       // u[n][p] (+bias)
        int n = id >> 6, p = id & 63;
        float r = ldE(kw1,p*3+0,f32)*ldE(xpos,n*3+0,f32)
                + ldE(kw1,p*3+1,f32)*ldE(xpos,n*3+1,f32)
                + ldE(kw1,p*3+2,f32)*ldE(xpos,n*3+2,f32) + ldE(kb1,p,f32);
        ws[OFF_U + id] = r;
    } else if (id < 32768) {                // w[m][p]
        int i = id - 16384; int m = i >> 6, p = i & 63;
        float r = ldE(kw1,p*3+0,f32)*ldE(ypos,m*3+0,f32)
                + ldE(kw1,p*3+1,f32)*ldE(ypos,m*3+1,f32)
                + ldE(kw1,p*3+2,f32)*ldE(ypos,m*3+2,f32);
        ws[OFF_W + i] = r;
    } else if (id < 40960) {                // Wphi[e][p]
        int i = id - 32768; int e = i >> 6, p = i & 63;
        float s = 0.f;
        for (int e2 = 0; e2 < 128; ++e2)
            s += ldE(phiw,e*384+256+e2,f32) * ldE(kw2,e2*64+p,f32);
        ws[OFF_WPHI + i] = s;
    } else if (id < 49152) {                // Wg[e][p]
        int i = id - 40960; int e = i >> 6, p = i & 63;
        float s = 0.f;
        for (int e2 = 0; e2 < 128; ++e2)
            s += ldE(gw,e*384+256+e2,f32) * ldE(kw2,e2*64+p,f32);
        ws[OFF_WG + i] = s;
    } else if (id < 49280) {                // phib[e]
        int e = id - 49152;
        float s = 0.f;
        for (int e2 = 0; e2 < 128; ++e2)
            s += ldE(phiw,e*384+256+e2,f32) * ldE(kb2,e2,f32);
        ws[OFF_PHIB + e] = s;
    } else if (id < 49408) {                // gb[e]
        int e = id - 49280;
        float s = 0.f;
        for (int e2 = 0; e2 < 128; ++e2)
            s += ldE(gw,e*384+256+e2,f32) * ldE(kb2,e2,f32);
        ws[OFF_GB + e] = s;
    }
}

// ---------------------------------------------------------------- K1: Ax / AyP / Gx / GyP
__global__ void __launch_bounds__(128) k1_proj(
    const void* __restrict__ x, const void* __restrict__ y,
    const void* __restrict__ phiw, const void* __restrict__ gw,
    float* __restrict__ ws)
{
    const bool f32 = ((const int*)ws)[0] != 0;
    int b = blockIdx.x;
    int which = b >> 8;          // 0:Ax 1:AyP 2:Gx 3:GyP
    int row = b & 255;
    const void* src = (which & 1) ? y : x;
    const void* wm  = (which < 2) ? phiw : gw;
    __shared__ float sr[256];
    int t = threadIdx.x;
    sr[t]     = ldE(src, row*256 + t, f32);
    sr[t+128] = ldE(src, row*256 + 128 + t, f32);
    __syncthreads();
    float acc = 0.f;
    float w8[8];
    #pragma unroll
    for (int i = 0; i < 32; ++i) {
        ld8(wm, t*384 + i*8, f32, w8);
        int d0 = i*8;
        #pragma unroll
        for (int j = 0; j < 8; ++j) acc += sr[d0+j]*w8[j];
    }
    float bias = 0.f;
    if (which == 1) bias = ws[OFF_PHIB + t];
    if (which == 3) bias = ws[OFF_GB + t];
    int base = (which==0) ? OFF_AX : (which==1) ? OFF_AYP : (which==2) ? OFF_GX : OFF_GYP;
    ws[base + row*128 + t] = acc - bias;
}

// ---------------------------------------------------------------- K2: q projection
__global__ void __launch_bounds__(128) k2_q(
    const void* __restrict__ x, const void* __restrict__ xpos,
    const void* __restrict__ qw1, const void* __restrict__ qb1,
    const void* __restrict__ qw2, const void* __restrict__ qb2,
    const void* __restrict__ thw, float* __restrict__ ws)
{
    const bool f32 = ((const int*)ws)[0] != 0;
    int n = blockIdx.x, t = threadIdx.x;
    __shared__ float hq[64];
    __shared__ float qpe[128];
    __shared__ float sx[256];
    sx[t]     = ldE(x, n*256 + t, f32);
    sx[t+128] = ldE(x, n*256 + 128 + t, f32);
    if (t < 64) {
        float r = ldE(qw1,t*3+0,f32)*ldE(xpos,n*3+0,f32)
                + ldE(qw1,t*3+1,f32)*ldE(xpos,n*3+1,f32)
                + ldE(qw1,t*3+2,f32)*ldE(xpos,n*3+2,f32) + ldE(qb1,t,f32);
        hq[t] = fmaxf(r, 0.f);
    }
    __syncthreads();
    float w8[8];
    {
        float s = ldE(qb2,t,f32);
        #pragma unroll
        for (int i = 0; i < 8; ++i) {
            ld8(qw2, t*64 + i*8, f32, w8);
            #pragma unroll
            for (int j = 0; j < 8; ++j) s += hq[i*8+j]*w8[j];
        }
        qpe[t] = s;
    }
    __syncthreads();
    float acc = 0.f;
    #pragma unroll
    for (int i = 0; i < 32; ++i) {
        ld8(thw, t*384 + i*8, f32, w8);
        #pragma unroll
        for (int j = 0; j < 8; ++j) acc += sx[i*8+j]*w8[j];
    }
    #pragma unroll
    for (int i = 0; i < 16; ++i) {
        ld8(thw, t*384 + 256 + i*8, f32, w8);
        #pragma unroll
        for (int j = 0; j < 8; ++j) acc += qpe[i*8+j]*w8[j];
    }
    ws[OFF_QS + n*128 + t] = acc * 0.17677669529663687f;  // * HD^-0.5
}

// ---------------------------------------------------------------- K3: fused k/v build + attention partials
// grid (c=64 chunks, h=4), 256 threads; each block does m = c*4..c*4+3, accumulating in regs.
__global__ void __launch_bounds__(256) k3_attn(float* __restrict__ ws)
{
    const int c = blockIdx.x;
    const int h = blockIdx.y;
    const int t = threadIdx.x;

    __shared__ float sWp[32*64];   // Wphi head slice (8 KB)
    __shared__ float sWg[32*64];   // Wg   head slice (8 KB)
    __shared__ float sW[64];
    __shared__ float sAy[128];
    __shared__ float sGy[128];
    __shared__ bf16  sKh[256*32];  // 16 KB
    __shared__ bf16  sVh[256*32];  // 16 KB

    {   // head-slice weights, loaded once
        const float4* p1 = (const float4*)(ws + OFF_WPHI + h*2048);
        const float4* p2 = (const float4*)(ws + OFF_WG   + h*2048);
        ((float4*)sWp)[t] = p1[t]; ((float4*)sWp)[t+256] = p1[t+256];
        ((float4*)sWg)[t] = p2[t]; ((float4*)sWg)[t+256] = p2[t+256];
    }

    float qreg[32];
    {
        const float4* qv = (const float4*)(ws + OFF_QS + t*128 + h*32);
        #pragma unroll
        for (int i = 0; i < 8; ++i) {
            float4 v = qv[i];
            qreg[i*4+0]=v.x; qreg[i*4+1]=v.y; qreg[i*4+2]=v.z; qreg[i*4+3]=v.w;
        }
    }
    float l = 0.f;
    float oacc[32];
    #pragma unroll
    for (int d = 0; d < 32; ++d) oacc[d] = 0.f;

    for (int mi = 0; mi < 4; ++mi) {
        const int m = c*4 + mi;
        __syncthreads();   // prior iteration's sKh/sVh consumers done; also covers sWp/sWg load
        if (t < 64) sW[t] = ws[OFF_W + m*64 + t];
        else if (t < 192) {
            int e = t - 64;
            sAy[e] = ws[OFF_AYP + m*128 + e];
            sGy[e] = ws[OFF_GYP + m*128 + e];
        }
        __syncthreads();

        // hact for key row t
        float hact[64];
        {
            const float4* uv = (const float4*)(ws + OFF_U + t*64);
            #pragma unroll
            for (int i = 0; i < 16; ++i) {
                float4 v = uv[i];
                hact[i*4+0] = fmaxf(v.x - sW[i*4+0], 0.f);
                hact[i*4+1] = fmaxf(v.y - sW[i*4+1], 0.f);
                hact[i*4+2] = fmaxf(v.z - sW[i*4+2], 0.f);
                hact[i*4+3] = fmaxf(v.w - sW[i*4+3], 0.f);
            }
        }

        // build K and V rows (key = t) into LDS (bf16)
        const float4* wp = (const float4*)sWp;
        const float4* wg = (const float4*)sWg;
        #pragma unroll 2
        for (int d = 0; d < 32; ++d) {
            float accK = ws[OFF_AX + t*128 + h*32 + d] - sAy[h*32+d];
            float accV = ws[OFF_GX + t*128 + h*32 + d] - sGy[h*32+d];
            #pragma unroll
            for (int i = 0; i < 16; ++i) {
                float4 a = wp[d*16+i];
                float4 b = wg[d*16+i];
                accK = fmaf(hact[i*4+0], a.x, accK);
                accK = fmaf(hact[i*4+1], a.y, accK);
                accK = fmaf(hact[i*4+2], a.z, accK);
                accK = fmaf(hact[i*4+3], a.w, accK);
                accV = fmaf(hact[i*4+0], b.x, accV);
                accV = fmaf(hact[i*4+1], b.y, accV);
                accV = fmaf(hact[i*4+2], b.z, accV);
                accV = fmaf(hact[i*4+3], b.w, accV);
            }
            sKh[t*32+d] = __float2bfloat16(accK);
            sVh[t*32+d] = __float2bfloat16(accV);
        }
        __syncthreads();

        // scores + exp + PV (thread t = query); max-free softmax (|s| small by construction)
        #pragma unroll 2
        for (int n = 0; n < 256; ++n) {
            const uint4* kr = (const uint4*)(sKh + n*32);
            float s = 0.f;
            #pragma unroll
            for (int i = 0; i < 4; ++i) {
                uint4 u = kr[i]; int d0 = i*8;
                s = fmaf(qreg[d0+0], u2f_lo(u.x), s);
                s = fmaf(qreg[d0+1], u2f_hi(u.x), s);
                s = fmaf(qreg[d0+2], u2f_lo(u.y), s);
                s = fmaf(qreg[d0+3], u2f_hi(u.y), s);
                s = fmaf(qreg[d0+4], u2f_lo(u.z), s);
                s = fmaf(qreg[d0+5], u2f_hi(u.z), s);
                s = fmaf(qreg[d0+6], u2f_lo(u.w), s);
                s = fmaf(qreg[d0+7], u2f_hi(u.w), s);
            }
            float pexp = __expf(s);
            l += pexp;
            const uint4* vr = (const uint4*)(sVh + n*32);
            #pragma unroll
            for (int i = 0; i < 4; ++i) {
                uint4 u = vr[i]; int d0 = i*8;
                oacc[d0+0] = fmaf(pexp, u2f_lo(u.x), oacc[d0+0]);
                oacc[d0+1] = fmaf(pexp, u2f_hi(u.x), oacc[d0+1]);
                oacc[d0+2] = fmaf(pexp, u2f_lo(u.y), oacc[d0+2]);
                oacc[d0+3] = fmaf(pexp, u2f_hi(u.y), oacc[d0+3]);
                oacc[d0+4] = fmaf(pexp, u2f_lo(u.z), oacc[d0+4]);
                oacc[d0+5] = fmaf(pexp, u2f_hi(u.z), oacc[d0+5]);
                oacc[d0+6] = fmaf(pexp, u2f_lo(u.w), oacc[d0+6]);
                oacc[d0+7] = fmaf(pexp, u2f_hi(u.w), oacc[d0+7]);
            }
        }
    }

    float* po = ws + OFF_PO + (size_t)((c*4 + h)*256 + t)*32;
    #pragma unroll
    for (int i = 0; i < 8; ++i)
        ((float4*)po)[i] = make_float4(oacc[i*4+0], oacc[i*4+1], oacc[i*4+2], oacc[i*4+3]);
    ws[OFF_PL + (c*4 + h)*256 + t] = l;
}

// ---------------------------------------------------------------- K4: merge + out proj + residual + LN
__global__ void __launch_bounds__(256) k4_out(
    const float* __restrict__ ws, const void* __restrict__ x,
    const void* __restrict__ outw, const void* __restrict__ lng,
    const void* __restrict__ lnb, void* __restrict__ outp)
{
    const bool f32 = ((const int*)ws)[0] != 0;
    int q = blockIdx.x, t = threadIdx.x;
    __shared__ float pl4[4][256];
    __shared__ float red[256];
    __shared__ float o2[128];
    __shared__ float stat[2];

    #pragma unroll
    for (int h = 0; h < 4; ++h)
        pl4[h][t] = (t < 64) ? ws[OFF_PL + (t*4 + h)*256 + q] : 0.f;
    __syncthreads();
    for (int s = 128; s > 0; s >>= 1) {
        if (t < s) {
            pl4[0][t] += pl4[0][t+s]; pl4[1][t] += pl4[1][t+s];
            pl4[2][t] += pl4[2][t+s]; pl4[3][t] += pl4[3][t+s];
        }
        __syncthreads();
    }
    int e = t & 127, h2 = e >> 5, d = e & 31, half = t >> 7;
    float a = 0.f;
    for (int mm = 0; mm < 32; ++mm) {
        int c = half*32 + mm;
        a += ws[OFF_PO + ((c*4 + h2)*256 + q)*32 + d];
    }
    red[t] = a;
    __syncthreads();
    if (t < 128) o2[t] = (red[t] + red[t+128]) / pl4[t>>5][0];
    __syncthreads();

    // out projection + residual
    float rv = ldE(x, q*256 + t, f32);
    float w8[8];
    #pragma unroll
    for (int i = 0; i < 16; ++i) {
        ld8(outw, t*128 + i*8, f32, w8);
        #pragma unroll
        for (int j = 0; j < 8; ++j) rv += o2[i*8+j]*w8[j];
    }
    // LayerNorm over 256 dims
    red[t] = rv; __syncthreads();
    for (int s = 128; s > 0; s >>= 1) { if (t < s) red[t] += red[t+s]; __syncthreads(); }
    if (t == 0) stat[0] = red[0] * (1.f/256.f);
    __syncthreads();
    float mu = stat[0];
    float dv = rv - mu;
    red[t] = dv*dv; __syncthreads();
    for (int s = 128; s > 0; s >>= 1) { if (t < s) red[t] += red[t+s]; __syncthreads(); }
    if (t == 0) stat[1] = red[0] * (1.f/256.f);
    __syncthreads();
    float rstd = rsqrtf(stat[1] + 1e-5f);
    float val = dv*rstd*ldE(lng,t,f32) + ldE(lnb,t,f32);
    if (f32) ((float*)outp)[q*256 + t] = val;
    else     ((bf16*)outp)[q*256 + t] = __float2bfloat16(val);
}

// ----------------------------------------------------------------
extern "C" void kernel_launch(void* const* d_in, const int* in_sizes, int n_in,
                              void* d_out, int out_size, void* d_ws, size_t ws_size,
                              hipStream_t stream)
{
    const void* x    = d_in[0];
    const void* y    = d_in[1];
    const void* xpos = d_in[2];
    const void* ypos = d_in[3];
    const void* thw  = d_in[4];
    const void* phiw = d_in[5];
    const void* gw   = d_in[6];
    const void* qw1  = d_in[7];
    const void* qb1  = d_in[8];
    const void* qw2  = d_in[9];
    const void* qb2  = d_in[10];
    const void* kw1  = d_in[11];
    const void* kb1  = d_in[12];
    const void* kw2  = d_in[13];
    const void* kb2  = d_in[14];
    const void* outw = d_in[15];
    const void* lng  = d_in[16];
    const void* lnb  = d_in[17];
    float* ws = (float*)d_ws;

    k_detect<<<1, 256, 0, stream>>>(x, (int*)d_ws);
    k0_prep<<<193, 256, 0, stream>>>(xpos, ypos, kw1, kb1, kw2, kb2, phiw, gw, ws);
    k1_proj<<<1024, 128, 0, stream>>>(x, y, phiw, gw, ws);
    k2_q<<<256, 128, 0, stream>>>(x, xpos, qw1, qb1, qw2, qb2, thw, ws);
    k3_attn<<<dim3(64, 4), 256, 0, stream>>>(ws);
    k4_out<<<256, 256, 0, stream>>>(ws, x, outw, lng, lnb, d_out);
}

// Round 3
// 249.440 us; speedup vs baseline: 2.2971x; 2.2971x over previous
//
#include <hip/hip_runtime.h>
#include <hip/hip_bf16.h>
#include <stdint.h>

// Problem: B=1, N=M=256, D=256, E=128, H=4, HD=32, P=64
typedef __hip_bfloat16 bf16;
typedef __attribute__((ext_vector_type(8))) short short8;
typedef __attribute__((ext_vector_type(4))) float f32x4;

__device__ __forceinline__ float b2f(bf16 v) { return __bfloat162float(v); }
__device__ __forceinline__ float u2f_lo(uint32_t u) { union { uint32_t u; float f; } c; c.u = u << 16;         return c.f; }
__device__ __forceinline__ float u2f_hi(uint32_t u) { union { uint32_t u; float f; } c; c.u = u & 0xffff0000u; return c.f; }
__device__ __forceinline__ short f2bs(float f) {
    __hip_bfloat16 h = __float2bfloat16(f);
    return *reinterpret_cast<short*>(&h);
}

// generic input loaders: flag-driven (inputs may be bf16 or f32)
__device__ __forceinline__ float ldE(const void* p, int i, bool f32) {
    return f32 ? ((const float*)p)[i] : b2f(((const bf16*)p)[i]);
}
__device__ __forceinline__ void ld8(const void* p, int base, bool f32, float* o) {
    if (f32) {
        const float4* q = (const float4*)((const float*)p + base);
        float4 a = q[0], b = q[1];
        o[0]=a.x; o[1]=a.y; o[2]=a.z; o[3]=a.w; o[4]=b.x; o[5]=b.y; o[6]=b.z; o[7]=b.w;
    } else {
        uint4 u = *((const uint4*)((const bf16*)p + base));
        o[0]=u2f_lo(u.x); o[1]=u2f_hi(u.x); o[2]=u2f_lo(u.y); o[3]=u2f_hi(u.y);
        o[4]=u2f_lo(u.z); o[5]=u2f_hi(u.z); o[6]=u2f_lo(u.w); o[7]=u2f_hi(u.w);
    }
}

// workspace layout (float offsets); ws[0] holds the dtype flag (int, 1 = f32 inputs)
#define OFF_U     8         // [256][64]  u = x_pos@k_w1^T + k_b1
#define OFF_W     16392     // [256][64]  w = y_pos@k_w1^T
#define OFF_WPHI  32776     // [128][64]  phi_pe @ k_w2   (f32)
#define OFF_WG    40968     // [128][64]  g_pe @ k_w2     (f32)
#define OFF_PHIB  49160     // [128]      phi_pe @ k_b2
#define OFF_GB    49288     // [128]      g_pe @ k_b2
#define OFF_QS    49416     // [256][128] q (scaled)
#define OFF_AX    82184     // [256][128] x @ phi_msg^T
#define OFF_AYP   114952    // [256][128] y @ phi_msg^T - phib
#define OFF_GX    147720    // [256][128] x @ g_msg^T
#define OFF_GYP   180488    // [256][128] y @ g_msg^T - gb
#define OFF_PO    213256    // [64 c][4 h][256 q][32]  partial sum(exp*v)
#define OFF_PL    2310408   // [64 c][4 h][256 q]      partial sum(exp)
#define OFF_WPB   2375944   // [128][64] bf16 copy of WPHI (8192 shorts = 4096 floats)
#define OFF_WGB   2380040   // [128][64] bf16 copy of WG
// total 2384136 floats = 9.54 MB

// ---------------------------------------------------------------- dtype detect
__global__ void k_detect(const void* __restrict__ x, int* __restrict__ flag) {
    __shared__ int cnt;
    if (threadIdx.x == 0) cnt = 0;
    __syncthreads();
    const uint32_t* w = (const uint32_t*)x;
    int c = 0;
    for (int i = threadIdx.x; i < 1024; i += 256) {
        uint32_t e = (w[i] >> 7) & 0xFFu;
        c += (e >= 96 && e <= 160) ? 1 : 0;
    }
    atomicAdd(&cnt, c);
    __syncthreads();
    if (threadIdx.x == 0) flag[0] = (cnt >= 640) ? 0 : 1;
}

// ---------------------------------------------------------------- K0: tiny precomputes
__global__ void __launch_bounds__(256) k0_prep(
    const void* __restrict__ xpos, const void* __restrict__ ypos,
    const void* __restrict__ kw1,  const void* __restrict__ kb1,
    const void* __restrict__ kw2,  const void* __restrict__ kb2,
    const void* __restrict__ phiw, const void* __restrict__ gw,
    float* __restrict__ ws)
{
    const bool f32 = ((const int*)ws)[0] != 0;
    int id = blockIdx.x * 256 + threadIdx.x;
    if (id < 16384) {                       // u[n][p] (+bias)
        int n = id >> 6, p = id & 63;
        float r = ldE(kw1,p*3+0,f32)*ldE(xpos,n*3+0,f32)
                + ldE(kw1,p*3+1,f32)*ldE(xpos,n*3+1,f32)
                + ldE(kw1,p*3+2,f32)*ldE(xpos,n*3+2,f32) + ldE(kb1,p,f32);
        ws[OFF_U + id] = r;
    } else if (id < 32768) {                // w[m][p]
        int i = id - 16384; int m = i >> 6, p = i & 63;
        float r = ldE(kw1,p*3+0,f32)*ldE(ypos,m*3+0,f32)
                + ldE(kw1,p*3+1,f32)*ldE(ypos,m*3+1,f32)
                + ldE(kw1,p*3+2,f32)*ldE(ypos,m*3+2,f32);
        ws[OFF_W + i] = r;
    } else if (id < 40960) {                // Wphi[e][p]
        int i = id - 32768; int e = i >> 6, p = i & 63;
        float s = 0.f;
        for (int e2 = 0; e2 < 128; ++e2)
            s += ldE(phiw,e*384+256+e2,f32) * ldE(kw2,e2*64+p,f32);
        ws[OFF_WPHI + i] = s;
    } else if (id < 49152) {                // Wg[e][p]
        int i = id - 40960; int e = i >> 6, p = i & 63;
        float s = 0.f;
        for (int e2 = 0; e2 < 128; ++e2)
            s += ldE(gw,e*384+256+e2,f32) * ldE(kw2,e2*64+p,f32);
        ws[OFF_WG + i] = s;
    } else if (id < 49280) {                // phib[e]
        int e = id - 49152;
        float s = 0.f;
        for (int e2 = 0; e2 < 128; ++e2)
            s += ldE(phiw,e*384+256+e2,f32) * ldE(kb2,e2,f32);
        ws[OFF_PHIB + e] = s;
    } else if (id < 49408) {                // gb[e]
        int e = id - 49280;
        float s = 0.f;
        for (int e2 = 0; e2 < 128; ++e2)
            s += ldE(gw,e*384+256+e2,f32) * ldE(kb2,e2,f32);
        ws[OFF_GB + e] = s;
    }
}

// ---------------------------------------------------------------- K0b: bf16 copies of Wphi/Wg
__global__ void __launch_bounds__(256) k0b_cvt(float* __restrict__ ws)
{
    int id = blockIdx.x * 256 + threadIdx.x;   // 0..16383
    short* wpb = (short*)(ws + OFF_WPB);
    short* wgb = (short*)(ws + OFF_WGB);
    if (id < 8192) wpb[id] = f2bs(ws[OFF_WPHI + id]);
    else           wgb[id - 8192] = f2bs(ws[OFF_WG + (id - 8192)]);
}

// ---------------------------------------------------------------- K1: Ax / AyP / Gx / GyP
__global__ void __launch_bounds__(128) k1_proj(
    const void* __restrict__ x, const void* __restrict__ y,
    const void* __restrict__ phiw, const void* __restrict__ gw,
    float* __restrict__ ws)
{
    const bool f32 = ((const int*)ws)[0] != 0;
    int b = blockIdx.x;
    int which = b >> 8;          // 0:Ax 1:AyP 2:Gx 3:GyP
    int row = b & 255;
    const void* src = (which & 1) ? y : x;
    const void* wm  = (which < 2) ? phiw : gw;
    __shared__ float sr[256];
    int t = threadIdx.x;
    sr[t]     = ldE(src, row*256 + t, f32);
    sr[t+128] = ldE(src, row*256 + 128 + t, f32);
    __syncthreads();
    float acc = 0.f;
    float w8[8];
    #pragma unroll
    for (int i = 0; i < 32; ++i) {
        ld8(wm, t*384 + i*8, f32, w8);
        int d0 = i*8;
        #pragma unroll
        for (int j = 0; j < 8; ++j) acc += sr[d0+j]*w8[j];
    }
    float bias = 0.f;
    if (which == 1) bias = ws[OFF_PHIB + t];
    if (which == 3) bias = ws[OFF_GB + t];
    int base = (which==0) ? OFF_AX : (which==1) ? OFF_AYP : (which==2) ? OFF_GX : OFF_GYP;
    ws[base + row*128 + t] = acc - bias;
}

// ---------------------------------------------------------------- K2: q projection
__global__ void __launch_bounds__(128) k2_q(
    const void* __restrict__ x, const void* __restrict__ xpos,
    const void* __restrict__ qw1, const void* __restrict__ qb1,
    const void* __restrict__ qw2, const void* __restrict__ qb2,
    const void* __restrict__ thw, float* __restrict__ ws)
{
    const bool f32 = ((const int*)ws)[0] != 0;
    int n = blockIdx.x, t = threadIdx.x;
    __shared__ float hq[64];
    __shared__ float qpe[128];
    __shared__ float sx[256];
    sx[t]     = ldE(x, n*256 + t, f32);
    sx[t+128] = ldE(x, n*256 + 128 + t, f32);
    if (t < 64) {
        float r = ldE(qw1,t*3+0,f32)*ldE(xpos,n*3+0,f32)
                + ldE(qw1,t*3+1,f32)*ldE(xpos,n*3+1,f32)
                + ldE(qw1,t*3+2,f32)*ldE(xpos,n*3+2,f32) + ldE(qb1,t,f32);
        hq[t] = fmaxf(r, 0.f);
    }
    __syncthreads();
    float w8[8];
    {
        float s = ldE(qb2,t,f32);
        #pragma unroll
        for (int i = 0; i < 8; ++i) {
            ld8(qw2, t*64 + i*8, f32, w8);
            #pragma unroll
            for (int j = 0; j < 8; ++j) s += hq[i*8+j]*w8[j];
        }
        qpe[t] = s;
    }
    __syncthreads();
    float acc = 0.f;
    #pragma unroll
    for (int i = 0; i < 32; ++i) {
        ld8(thw, t*384 + i*8, f32, w8);
        #pragma unroll
        for (int j = 0; j < 8; ++j) acc += sx[i*8+j]*w8[j];
    }
    #pragma unroll
    for (int i = 0; i < 16; ++i) {
        ld8(thw, t*384 + 256 + i*8, f32, w8);
        #pragma unroll
        for (int j = 0; j < 8; ++j) acc += qpe[i*8+j]*w8[j];
    }
    ws[OFF_QS + n*128 + t] = acc * 0.17677669529663687f;  // * HD^-0.5
}

// ---------------------------------------------------------------- K3: MFMA k/v build + attention partials
// grid (c=64, h=4), 512 threads (8 waves). Block handles m = c*4..c*4+3.
// MFMA 16x16x32 bf16 layouts (HW-verified):
//   A: lane holds A[row=lane&15][k=(lane>>4)*8+j]  (j=0..7)
//   B: lane holds B[k=(lane>>4)*8+j][col=lane&15]
//   C/D: lane holds C[row=(lane>>4)*4+r][col=lane&15]  (r=0..3)
__global__ void __launch_bounds__(512) k3_attn(float* __restrict__ ws)
{
    const int c = blockIdx.x, h = blockIdx.y;
    const int tid = threadIdx.x;
    const int w = tid >> 6, lane = tid & 63;
    const int quad = lane >> 4, l16 = lane & 15;

    __shared__ float sW[64];
    __shared__ float sAy[32];
    __shared__ float sGy[32];
    __shared__ alignas(16) short s_hact[256*72];   // [key][p], stride 72 (pad)  36 KB
    __shared__ alignas(16) short s_k[256*40];      // [key][d], stride 40        20 KB
    __shared__ alignas(16) short s_vt[32*264];     // [d][key], stride 264       16.5 KB
    __shared__ alignas(16) short s_p[8*2*16*40];   // per-wave x2 P buf          20 KB

    // Q A-fragments for this wave's two q-tiles (qt = w*2 + qt2)
    short8 qa[2];
    #pragma unroll
    for (int qt2 = 0; qt2 < 2; ++qt2) {
        const float* qp = ws + OFF_QS + (size_t)((w*2+qt2)*16 + l16)*128 + h*32 + quad*8;
        short8 v;
        #pragma unroll
        for (int j = 0; j < 8; ++j) v[j] = f2bs(qp[j]);
        qa[qt2] = v;
    }

    f32x4 o[2][2];
    float lp[2][4];
    #pragma unroll
    for (int a = 0; a < 2; ++a) {
        #pragma unroll
        for (int d = 0; d < 2; ++d) { o[a][d][0]=0.f; o[a][d][1]=0.f; o[a][d][2]=0.f; o[a][d][3]=0.f; }
        #pragma unroll
        for (int r = 0; r < 4; ++r) lp[a][r] = 0.f;
    }

    // build-phase wave role: which (0=K,1=V), d-tile, key-tile group
    const int which = w & 1, dtb = (w >> 1) & 1, ktg = w >> 2;
    const short* wbm = (const short*)(ws + (which ? OFF_WGB : OFF_WPB));
    const int ecol = h*32 + dtb*16 + l16;          // global E column this lane builds
    const short8 wb0 = *(const short8*)(wbm + ecol*64 + quad*8);
    const short8 wb1 = *(const short8*)(wbm + ecol*64 + 32 + quad*8);
    const float* xb = ws + (which ? OFF_GX : OFF_AX);

    for (int mi = 0; mi < 4; ++mi) {
        const int m = c*4 + mi;
        __syncthreads();
        if (tid < 64)       sW[tid]      = ws[OFF_W + m*64 + tid];
        else if (tid < 96)  sAy[tid-64]  = ws[OFF_AYP + m*128 + h*32 + (tid-64)];
        else if (tid < 128) sGy[tid-96]  = ws[OFF_GYP + m*128 + h*32 + (tid-96)];
        __syncthreads();

        // ---- hact[key][p] = relu(u[key][p] - w[m][p]) -> bf16 LDS
        {
            const int key = tid >> 1, half = tid & 1;
            const float4* up = (const float4*)(ws + OFF_U + key*64 + half*32);
            short* hd = s_hact + key*72 + half*32;
            #pragma unroll
            for (int i = 0; i < 8; ++i) {
                float4 u4 = up[i]; int p = half*32 + i*4;
                hd[i*4+0] = f2bs(fmaxf(u4.x - sW[p+0], 0.f));
                hd[i*4+1] = f2bs(fmaxf(u4.y - sW[p+1], 0.f));
                hd[i*4+2] = f2bs(fmaxf(u4.z - sW[p+2], 0.f));
                hd[i*4+3] = f2bs(fmaxf(u4.w - sW[p+3], 0.f));
            }
        }
        __syncthreads();

        // ---- K/V build via MFMA: D[key][d] = (Ax|Gx)[key][e] - (Ay|Gy)[e] + hact @ W
        {
            const float ycol = (which ? sGy : sAy)[dtb*16 + l16];
            #pragma unroll 2
            for (int i = 0; i < 8; ++i) {
                const int kt = ktg*8 + i;
                f32x4 acc;
                #pragma unroll
                for (int r = 0; r < 4; ++r)
                    acc[r] = xb[(size_t)(kt*16 + quad*4 + r)*128 + ecol] - ycol;
                const short8 a0 = *(const short8*)(s_hact + (kt*16 + l16)*72 + quad*8);
                const short8 a1 = *(const short8*)(s_hact + (kt*16 + l16)*72 + 32 + quad*8);
                acc = __builtin_amdgcn_mfma_f32_16x16x32_bf16(a0, wb0, acc, 0, 0, 0);
                acc = __builtin_amdgcn_mfma_f32_16x16x32_bf16(a1, wb1, acc, 0, 0, 0);
                if (which == 0) {
                    #pragma unroll
                    for (int r = 0; r < 4; ++r)
                        s_k[(kt*16 + quad*4 + r)*40 + dtb*16 + l16] = f2bs(acc[r]);
                } else {
                    #pragma unroll
                    for (int r = 0; r < 4; ++r)
                        s_vt[(dtb*16 + l16)*264 + kt*16 + quad*4 + r] = f2bs(acc[r]);
                }
            }
        }
        __syncthreads();

        // ---- attention: per 32-key chunk: scores -> exp -> P(LDS) -> PV
        for (int kc = 0; kc < 8; ++kc) {
            const short8 kb0 = *(const short8*)(s_k + (kc*32 + l16)*40 + quad*8);
            const short8 kb1 = *(const short8*)(s_k + (kc*32 + 16 + l16)*40 + quad*8);
            const short8 vb0 = *(const short8*)(s_vt + l16*264 + kc*32 + quad*8);
            const short8 vb1 = *(const short8*)(s_vt + (16 + l16)*264 + kc*32 + quad*8);
            #pragma unroll
            for (int qt2 = 0; qt2 < 2; ++qt2) {
                f32x4 z; z[0]=0.f; z[1]=0.f; z[2]=0.f; z[3]=0.f;
                f32x4 s0 = __builtin_amdgcn_mfma_f32_16x16x32_bf16(qa[qt2], kb0, z, 0, 0, 0);
                f32x4 s1 = __builtin_amdgcn_mfma_f32_16x16x32_bf16(qa[qt2], kb1, z, 0, 0, 0);
                short* pb = s_p + (w*2 + qt2)*640;   // per-wave double buffer
                #pragma unroll
                for (int r = 0; r < 4; ++r) {
                    float e0 = __expf(s0[r]);
                    float e1 = __expf(s1[r]);
                    lp[qt2][r] += e0 + e1;
                    pb[(quad*4+r)*40 + l16]      = f2bs(e0);
                    pb[(quad*4+r)*40 + 16 + l16] = f2bs(e1);
                }
                const short8 pa = *(const short8*)(pb + l16*40 + quad*8);
                o[qt2][0] = __builtin_amdgcn_mfma_f32_16x16x32_bf16(pa, vb0, o[qt2][0], 0, 0, 0);
                o[qt2][1] = __builtin_amdgcn_mfma_f32_16x16x32_bf16(pa, vb1, o[qt2][1], 0, 0, 0);
            }
        }
    }

    // ---- write partials (same layout as before: PO[(c*4+h)*256+q][32], PL[(c*4+h)*256+q])
    #pragma unroll
    for (int qt2 = 0; qt2 < 2; ++qt2) {
        #pragma unroll
        for (int dtl = 0; dtl < 2; ++dtl) {
            #pragma unroll
            for (int r = 0; r < 4; ++r) {
                int q = (w*2+qt2)*16 + quad*4 + r;
                ws[OFF_PO + (size_t)((c*4 + h)*256 + q)*32 + dtl*16 + l16] = o[qt2][dtl][r];
            }
        }
        #pragma unroll
        for (int r = 0; r < 4; ++r) {
            float v = lp[qt2][r];
            v += __shfl_xor(v, 1); v += __shfl_xor(v, 2);
            v += __shfl_xor(v, 4); v += __shfl_xor(v, 8);
            if (l16 == 0)
                ws[OFF_PL + (c*4 + h)*256 + (w*2+qt2)*16 + quad*4 + r] = v;
        }
    }
}

// ---------------------------------------------------------------- K4: merge + out proj + residual + LN
__global__ void __launch_bounds__(256) k4_out(
    const float* __restrict__ ws, const void* __restrict__ x,
    const void* __restrict__ outw, const void* __restrict__ lng,
    const void* __restrict__ lnb, void* __restrict__ outp)
{
    const bool f32 = ((const int*)ws)[0] != 0;
    int q = blockIdx.x, t = threadIdx.x;
    __shared__ float pl4[4][256];
    __shared__ float red[256];
    __shared__ float o2[128];
    __shared__ float stat[2];

    #pragma unroll
    for (int h = 0; h < 4; ++h)
        pl4[h][t] = (t < 64) ? ws[OFF_PL + (t*4 + h)*256 + q] : 0.f;
    __syncthreads();
    for (int s = 128; s > 0; s >>= 1) {
        if (t < s) {
            pl4[0][t] += pl4[0][t+s]; pl4[1][t] += pl4[1][t+s];
            pl4[2][t] += pl4[2][t+s]; pl4[3][t] += pl4[3][t+s];
        }
        __syncthreads();
    }
    int e = t & 127, h2 = e >> 5, d = e & 31, half = t >> 7;
    float a = 0.f;
    for (int mm = 0; mm < 32; ++mm) {
        int c = half*32 + mm;
        a += ws[OFF_PO + ((c*4 + h2)*256 + q)*32 + d];
    }
    red[t] = a;
    __syncthreads();
    if (t < 128) o2[t] = (red[t] + red[t+128]) / pl4[t>>5][0];
    __syncthreads();

    float rv = ldE(x, q*256 + t, f32);
    float w8[8];
    #pragma unroll
    for (int i = 0; i < 16; ++i) {
        ld8(outw, t*128 + i*8, f32, w8);
        #pragma unroll
        for (int j = 0; j < 8; ++j) rv += o2[i*8+j]*w8[j];
    }
    red[t] = rv; __syncthreads();
    for (int s = 128; s > 0; s >>= 1) { if (t < s) red[t] += red[t+s]; __syncthreads(); }
    if (t == 0) stat[0] = red[0] * (1.f/256.f);
    __syncthreads();
    float mu = stat[0];
    float dv = rv - mu;
    red[t] = dv*dv; __syncthreads();
    for (int s = 128; s > 0; s >>= 1) { if (t < s) red[t] += red[t+s]; __syncthreads(); }
    if (t == 0) stat[1] = red[0] * (1.f/256.f);
    __syncthreads();
    float rstd = rsqrtf(stat[1] + 1e-5f);
    float val = dv*rstd*ldE(lng,t,f32) + ldE(lnb,t,f32);
    if (f32) ((float*)outp)[q*256 + t] = val;
    else     ((bf16*)outp)[q*256 + t] = __float2bfloat16(val);
}

// ----------------------------------------------------------------
extern "C" void kernel_launch(void* const* d_in, const int* in_sizes, int n_in,
                              void* d_out, int out_size, void* d_ws, size_t ws_size,
                              hipStream_t stream)
{
    const void* x    = d_in[0];
    const void* y    = d_in[1];
    const void* xpos = d_in[2];
    const void* ypos = d_in[3];
    const void* thw  = d_in[4];
    const void* phiw = d_in[5];
    const void* gw   = d_in[6];
    const void* qw1  = d_in[7];
    const void* qb1  = d_in[8];
    const void* qw2  = d_in[9];
    const void* qb2  = d_in[10];
    const void* kw1  = d_in[11];
    const void* kb1  = d_in[12];
    const void* kw2  = d_in[13];
    const void* kb2  = d_in[14];
    const void* outw = d_in[15];
    const void* lng  = d_in[16];
    const void* lnb  = d_in[17];
    float* ws = (float*)d_ws;

    k_detect<<<1, 256, 0, stream>>>(x, (int*)d_ws);
    k0_prep<<<193, 256, 0, stream>>>(xpos, ypos, kw1, kb1, kw2, kb2, phiw, gw, ws);
    k0b_cvt<<<64, 256, 0, stream>>>(ws);
    k1_proj<<<1024, 128, 0, stream>>>(x, y, phiw, gw, ws);
    k2_q<<<256, 128, 0, stream>>>(x, xpos, qw1, qb1, qw2, qb2, thw, ws);
    k3_attn<<<dim3(64, 4), 512, 0, stream>>>(ws);
    k4_out<<<256, 256, 0, stream>>>(ws, x, outw, lng, lnb, d_out);
}

// Round 4
// 205.533 us; speedup vs baseline: 2.7878x; 1.2136x over previous
//
#include <hip/hip_runtime.h>
#include <hip/hip_bf16.h>
#include <stdint.h>

// Problem: B=1, N=M=256, D=256, E=128, H=4, HD=32, P=64
typedef __hip_bfloat16 bf16;
typedef __attribute__((ext_vector_type(8))) short short8;
typedef __attribute__((ext_vector_type(4))) float f32x4;

__device__ __forceinline__ float b2f(bf16 v) { return __bfloat162float(v); }
__device__ __forceinline__ float u2f_lo(uint32_t u) { union { uint32_t u; float f; } c; c.u = u << 16;         return c.f; }
__device__ __forceinline__ float u2f_hi(uint32_t u) { union { uint32_t u; float f; } c; c.u = u & 0xffff0000u; return c.f; }
__device__ __forceinline__ short f2bs(float f) {
    __hip_bfloat16 h = __float2bfloat16(f);
    return *reinterpret_cast<short*>(&h);
}

// generic input loaders: flag-driven (inputs may be bf16 or f32)
__device__ __forceinline__ float ldE(const void* p, int i, bool f32) {
    return f32 ? ((const float*)p)[i] : b2f(((const bf16*)p)[i]);
}

// workspace layout (float offsets); ws[0] holds the dtype flag (int, 1 = f32 inputs)
#define OFF_U     8         // [256][64]  u = x_pos@k_w1^T + k_b1           (f32)
#define OFF_W     16392     // [256][64]  w = y_pos@k_w1^T                  (f32)
#define OFF_WPHI  32776     // [128][64]  phi_pe @ k_w2                     (f32)
#define OFF_WG    40968     // [128][64]  g_pe @ k_w2                       (f32)
#define OFF_PHIB  49160     // [128]      phi_pe @ k_b2
#define OFF_GB    49288     // [128]      g_pe @ k_b2
#define OFF_QS    49416     // [256][128] q (scaled)                        (f32)
#define OFF_AX    82184     // [256][128] x @ phi_msg^T                     (f32)
#define OFF_AYP   114952    // [256][128] y @ phi_msg^T - phib              (f32)
#define OFF_GX    147720    // [256][128] x @ g_msg^T                       (f32)
#define OFF_GYP   180488    // [256][128] y @ g_msg^T - gb                  (f32)
#define OFF_PO    213256    // [64 c][4 h][256 q][32]  partial sum(exp*v)   (f32)
#define OFF_PL    2310408   // [64 c][4 h][256 q]      partial sum(exp)     (f32)
#define OFF_WPB   2375944   // [128][64]  bf16 WPHI
#define OFF_WGB   2380040   // [128][64]  bf16 WG
#define OFF_XB    2384136   // [256][256] bf16 x
#define OFF_YB    2400520   // [256][256] bf16 y
#define OFF_QPB   2416904   // [256][128] bf16 qpe
#define OFF_THB   2433288   // [128][384] bf16 theta_w
#define OFF_PWB   2457864   // [128][256] bf16 phi_msg
#define OFF_GWB   2474248   // [128][256] bf16 g_msg
// total 2490632 floats = 9.96 MB

// ---------------------------------------------------------------- dtype detect
__global__ void k_detect(const void* __restrict__ x, int* __restrict__ flag) {
    __shared__ int cnt;
    if (threadIdx.x == 0) cnt = 0;
    __syncthreads();
    const uint32_t* w = (const uint32_t*)x;
    int c = 0;
    for (int i = threadIdx.x; i < 1024; i += 256) {
        uint32_t e = (w[i] >> 7) & 0xFFu;
        c += (e >= 96 && e <= 160) ? 1 : 0;
    }
    atomicAdd(&cnt, c);
    __syncthreads();
    if (threadIdx.x == 0) flag[0] = (cnt >= 640) ? 0 : 1;
}

// ---------------------------------------------------------------- K0: precomputes + bf16 staging
__global__ void __launch_bounds__(256) k0_prep(
    const void* __restrict__ x,    const void* __restrict__ y,
    const void* __restrict__ xpos, const void* __restrict__ ypos,
    const void* __restrict__ thw,  const void* __restrict__ phiw,
    const void* __restrict__ gw,
    const void* __restrict__ qw1,  const void* __restrict__ qb1,
    const void* __restrict__ qw2,  const void* __restrict__ qb2,
    const void* __restrict__ kw1,  const void* __restrict__ kb1,
    const void* __restrict__ kw2,  const void* __restrict__ kb2,
    float* __restrict__ ws)
{
    const bool f32 = ((const int*)ws)[0] != 0;
    int id = blockIdx.x * 256 + threadIdx.x;
    if (id < 16384) {                       // u[n][p] (+bias)
        int n = id >> 6, p = id & 63;
        float r = ldE(kw1,p*3+0,f32)*ldE(xpos,n*3+0,f32)
                + ldE(kw1,p*3+1,f32)*ldE(xpos,n*3+1,f32)
                + ldE(kw1,p*3+2,f32)*ldE(xpos,n*3+2,f32) + ldE(kb1,p,f32);
        ws[OFF_U + id] = r;
    } else if (id < 32768) {                // w[m][p]
        int i = id - 16384; int m = i >> 6, p = i & 63;
        float r = ldE(kw1,p*3+0,f32)*ldE(ypos,m*3+0,f32)
                + ldE(kw1,p*3+1,f32)*ldE(ypos,m*3+1,f32)
                + ldE(kw1,p*3+2,f32)*ldE(ypos,m*3+2,f32);
        ws[OFF_W + i] = r;
    } else if (id < 40960) {                // Wphi[e][p] (f32 + bf16)
        int i = id - 32768; int e = i >> 6, p = i & 63;
        float s = 0.f;
        for (int e2 = 0; e2 < 128; ++e2)
            s += ldE(phiw,e*384+256+e2,f32) * ldE(kw2,e2*64+p,f32);
        ws[OFF_WPHI + i] = s;
        ((short*)(ws + OFF_WPB))[i] = f2bs(s);
    } else if (id < 49152) {                // Wg[e][p] (f32 + bf16)
        int i = id - 40960; int e = i >> 6, p = i & 63;
        float s = 0.f;
        for (int e2 = 0; e2 < 128; ++e2)
            s += ldE(gw,e*384+256+e2,f32) * ldE(kw2,e2*64+p,f32);
        ws[OFF_WG + i] = s;
        ((short*)(ws + OFF_WGB))[i] = f2bs(s);
    } else if (id < 49280) {                // phib[e]
        int e = id - 49152;
        float s = 0.f;
        for (int e2 = 0; e2 < 128; ++e2)
            s += ldE(phiw,e*384+256+e2,f32) * ldE(kb2,e2,f32);
        ws[OFF_PHIB + e] = s;
    } else if (id < 49408) {                // gb[e]
        int e = id - 49280;
        float s = 0.f;
        for (int e2 = 0; e2 < 128; ++e2)
            s += ldE(gw,e*384+256+e2,f32) * ldE(kb2,e2,f32);
        ws[OFF_GB + e] = s;
    } else if (id < 114944) {               // xb
        int i = id - 49408;
        ((short*)(ws + OFF_XB))[i] = f2bs(ldE(x, i, f32));
    } else if (id < 180480) {               // yb
        int i = id - 114944;
        ((short*)(ws + OFF_YB))[i] = f2bs(ldE(y, i, f32));
    } else if (id < 229632) {               // thwb
        int i = id - 180480;
        ((short*)(ws + OFF_THB))[i] = f2bs(ldE(thw, i, f32));
    } else if (id < 262400) {               // phiwb (msg part, cols 0..255)
        int i = id - 229632; int e = i >> 8, d = i & 255;
        ((short*)(ws + OFF_PWB))[i] = f2bs(ldE(phiw, e*384+d, f32));
    } else if (id < 295168) {               // gwb (msg part)
        int i = id - 262400; int e = i >> 8, d = i & 255;
        ((short*)(ws + OFF_GWB))[i] = f2bs(ldE(gw, e*384+d, f32));
    } else if (id < 327936) {               // qpe[n][e] (bf16), hidden MLP recomputed
        int i = id - 295168; int n = i & 255, e = i >> 8;
        float px = ldE(xpos,n*3+0,f32), py = ldE(xpos,n*3+1,f32), pz = ldE(xpos,n*3+2,f32);
        float s = ldE(qb2,e,f32);
        for (int p = 0; p < 64; ++p) {
            float hq = fmaxf(ldE(qw1,p*3+0,f32)*px + ldE(qw1,p*3+1,f32)*py
                           + ldE(qw1,p*3+2,f32)*pz + ldE(qb1,p,f32), 0.f);
            s += hq * ldE(qw2,e*64+p,f32);
        }
        ((short*)(ws + OFF_QPB))[n*128 + e] = f2bs(s);
    }
}

// ---------------------------------------------------------------- K1: Ax/AyP/Gx/GyP via MFMA
// grid 16 blocks = which(4) x rowgroup(4); 256 thr = 4 waves x 16 rows.
__global__ void __launch_bounds__(256) k1_gemm(float* __restrict__ ws)
{
    const int which = blockIdx.x >> 2, rg = blockIdx.x & 3;
    const int w = threadIdx.x >> 6, lane = threadIdx.x & 63;
    const int quad = lane >> 4, l16 = lane & 15;
    const short* ab = (const short*)(ws + ((which & 1) ? OFF_YB : OFF_XB));
    const short* bb = (const short*)(ws + ((which < 2) ? OFF_PWB : OFF_GWB));
    const int row0 = rg*64 + w*16;

    f32x4 acc[8];
    #pragma unroll
    for (int ct = 0; ct < 8; ++ct) { acc[ct][0]=0.f; acc[ct][1]=0.f; acc[ct][2]=0.f; acc[ct][3]=0.f; }

    #pragma unroll 2
    for (int k = 0; k < 8; ++k) {
        const short8 af = *(const short8*)(ab + (row0 + l16)*256 + k*32 + quad*8);
        #pragma unroll
        for (int ct = 0; ct < 8; ++ct) {
            const short8 bf = *(const short8*)(bb + (ct*16 + l16)*256 + k*32 + quad*8);
            acc[ct] = __builtin_amdgcn_mfma_f32_16x16x32_bf16(af, bf, acc[ct], 0, 0, 0);
        }
    }
    const int base = (which==0) ? OFF_AX : (which==1) ? OFF_AYP : (which==2) ? OFF_GX : OFF_GYP;
    #pragma unroll
    for (int ct = 0; ct < 8; ++ct) {
        float bias = 0.f;
        if (which == 1) bias = ws[OFF_PHIB + ct*16 + l16];
        if (which == 3) bias = ws[OFF_GB + ct*16 + l16];
        #pragma unroll
        for (int r = 0; r < 4; ++r)
            ws[base + (row0 + quad*4 + r)*128 + ct*16 + l16] = acc[ct][r] - bias;
    }
}

// ---------------------------------------------------------------- K2: q = [xb|qpeb] @ thw^T via MFMA
// grid 4 blocks (64 rows each); 256 thr = 4 waves x 16 rows.
__global__ void __launch_bounds__(256) k2_gemm(float* __restrict__ ws)
{
    const int rg = blockIdx.x;
    const int w = threadIdx.x >> 6, lane = threadIdx.x & 63;
    const int quad = lane >> 4, l16 = lane & 15;
    const short* xbs = (const short*)(ws + OFF_XB);
    const short* qps = (const short*)(ws + OFF_QPB);
    const short* bb  = (const short*)(ws + OFF_THB);
    const int row0 = rg*64 + w*16;

    f32x4 acc[8];
    #pragma unroll
    for (int ct = 0; ct < 8; ++ct) { acc[ct][0]=0.f; acc[ct][1]=0.f; acc[ct][2]=0.f; acc[ct][3]=0.f; }

    for (int k = 0; k < 12; ++k) {
        const short8 af = (k < 8)
            ? *(const short8*)(xbs + (row0 + l16)*256 + k*32 + quad*8)
            : *(const short8*)(qps + (row0 + l16)*128 + (k-8)*32 + quad*8);
        #pragma unroll
        for (int ct = 0; ct < 8; ++ct) {
            const short8 bf = *(const short8*)(bb + (ct*16 + l16)*384 + k*32 + quad*8);
            acc[ct] = __builtin_amdgcn_mfma_f32_16x16x32_bf16(af, bf, acc[ct], 0, 0, 0);
        }
    }
    #pragma unroll
    for (int ct = 0; ct < 8; ++ct)
        #pragma unroll
        for (int r = 0; r < 4; ++r)
            ws[OFF_QS + (row0 + quad*4 + r)*128 + ct*16 + l16] =
                acc[ct][r] * 0.17677669529663687f;
}

// ---------------------------------------------------------------- K3: MFMA k/v build + attention partials
// grid (c=64, h=4), 512 threads (8 waves). Block handles m = c*4..c*4+3.
__global__ void __launch_bounds__(512) k3_attn(float* __restrict__ ws)
{
    const int c = blockIdx.x, h = blockIdx.y;
    const int tid = threadIdx.x;
    const int w = tid >> 6, lane = tid & 63;
    const int quad = lane >> 4, l16 = lane & 15;

    __shared__ float sW[64];
    __shared__ float sAy[32];
    __shared__ float sGy[32];
    __shared__ alignas(16) short s_hact[256*72];   // [key][p], stride 72 (pad)  36 KB
    __shared__ alignas(16) short s_k[256*40];      // [key][d], stride 40        20 KB
    __shared__ alignas(16) short s_vt[32*264];     // [d][key], stride 264       16.5 KB
    __shared__ alignas(16) short s_p[8*2*16*40];   // per-wave x2 P buf          20 KB

    short8 qa[2];
    #pragma unroll
    for (int qt2 = 0; qt2 < 2; ++qt2) {
        const float* qp = ws + OFF_QS + (size_t)((w*2+qt2)*16 + l16)*128 + h*32 + quad*8;
        short8 v;
        #pragma unroll
        for (int j = 0; j < 8; ++j) v[j] = f2bs(qp[j]);
        qa[qt2] = v;
    }

    f32x4 o[2][2];
    float lp[2][4];
    #pragma unroll
    for (int a = 0; a < 2; ++a) {
        #pragma unroll
        for (int d = 0; d < 2; ++d) { o[a][d][0]=0.f; o[a][d][1]=0.f; o[a][d][2]=0.f; o[a][d][3]=0.f; }
        #pragma unroll
        for (int r = 0; r < 4; ++r) lp[a][r] = 0.f;
    }

    const int which = w & 1, dtb = (w >> 1) & 1, ktg = w >> 2;
    const short* wbm = (const short*)(ws + (which ? OFF_WGB : OFF_WPB));
    const int ecol = h*32 + dtb*16 + l16;
    const short8 wb0 = *(const short8*)(wbm + ecol*64 + quad*8);
    const short8 wb1 = *(const short8*)(wbm + ecol*64 + 32 + quad*8);
    const float* xb = ws + (which ? OFF_GX : OFF_AX);

    for (int mi = 0; mi < 4; ++mi) {
        const int m = c*4 + mi;
        __syncthreads();
        if (tid < 64)       sW[tid]      = ws[OFF_W + m*64 + tid];
        else if (tid < 96)  sAy[tid-64]  = ws[OFF_AYP + m*128 + h*32 + (tid-64)];
        else if (tid < 128) sGy[tid-96]  = ws[OFF_GYP + m*128 + h*32 + (tid-96)];
        __syncthreads();

        {   // hact[key][p] = relu(u[key][p] - w[m][p])
            const int key = tid >> 1, half = tid & 1;
            const float4* up = (const float4*)(ws + OFF_U + key*64 + half*32);
            short* hd = s_hact + key*72 + half*32;
            #pragma unroll
            for (int i = 0; i < 8; ++i) {
                float4 u4 = up[i]; int p = half*32 + i*4;
                hd[i*4+0] = f2bs(fmaxf(u4.x - sW[p+0], 0.f));
                hd[i*4+1] = f2bs(fmaxf(u4.y - sW[p+1], 0.f));
                hd[i*4+2] = f2bs(fmaxf(u4.z - sW[p+2], 0.f));
                hd[i*4+3] = f2bs(fmaxf(u4.w - sW[p+3], 0.f));
            }
        }
        __syncthreads();

        {   // K/V build via MFMA
            const float ycol = (which ? sGy : sAy)[dtb*16 + l16];
            #pragma unroll 2
            for (int i = 0; i < 8; ++i) {
                const int kt = ktg*8 + i;
                f32x4 acc;
                #pragma unroll
                for (int r = 0; r < 4; ++r)
                    acc[r] = xb[(size_t)(kt*16 + quad*4 + r)*128 + ecol] - ycol;
                const short8 a0 = *(const short8*)(s_hact + (kt*16 + l16)*72 + quad*8);
                const short8 a1 = *(const short8*)(s_hact + (kt*16 + l16)*72 + 32 + quad*8);
                acc = __builtin_amdgcn_mfma_f32_16x16x32_bf16(a0, wb0, acc, 0, 0, 0);
                acc = __builtin_amdgcn_mfma_f32_16x16x32_bf16(a1, wb1, acc, 0, 0, 0);
                if (which == 0) {
                    #pragma unroll
                    for (int r = 0; r < 4; ++r)
                        s_k[(kt*16 + quad*4 + r)*40 + dtb*16 + l16] = f2bs(acc[r]);
                } else {
                    #pragma unroll
                    for (int r = 0; r < 4; ++r)
                        s_vt[(dtb*16 + l16)*264 + kt*16 + quad*4 + r] = f2bs(acc[r]);
                }
            }
        }
        __syncthreads();

        // attention: per 32-key chunk: scores -> exp -> P(LDS) -> PV
        for (int kc = 0; kc < 8; ++kc) {
            const short8 kb0 = *(const short8*)(s_k + (kc*32 + l16)*40 + quad*8);
            const short8 kb1 = *(const short8*)(s_k + (kc*32 + 16 + l16)*40 + quad*8);
            const short8 vb0 = *(const short8*)(s_vt + l16*264 + kc*32 + quad*8);
            const short8 vb1 = *(const short8*)(s_vt + (16 + l16)*264 + kc*32 + quad*8);
            #pragma unroll
            for (int qt2 = 0; qt2 < 2; ++qt2) {
                f32x4 z; z[0]=0.f; z[1]=0.f; z[2]=0.f; z[3]=0.f;
                f32x4 s0 = __builtin_amdgcn_mfma_f32_16x16x32_bf16(qa[qt2], kb0, z, 0, 0, 0);
                f32x4 s1 = __builtin_amdgcn_mfma_f32_16x16x32_bf16(qa[qt2], kb1, z, 0, 0, 0);
                short* pb = s_p + (w*2 + qt2)*640;
                #pragma unroll
                for (int r = 0; r < 4; ++r) {
                    float e0 = __expf(s0[r]);
                    float e1 = __expf(s1[r]);
                    lp[qt2][r] += e0 + e1;
                    pb[(quad*4+r)*40 + l16]      = f2bs(e0);
                    pb[(quad*4+r)*40 + 16 + l16] = f2bs(e1);
                }
                const short8 pa = *(const short8*)(pb + l16*40 + quad*8);
                o[qt2][0] = __builtin_amdgcn_mfma_f32_16x16x32_bf16(pa, vb0, o[qt2][0], 0, 0, 0);
                o[qt2][1] = __builtin_amdgcn_mfma_f32_16x16x32_bf16(pa, vb1, o[qt2][1], 0, 0, 0);
            }
        }
    }

    #pragma unroll
    for (int qt2 = 0; qt2 < 2; ++qt2) {
        #pragma unroll
        for (int dtl = 0; dtl < 2; ++dtl) {
            #pragma unroll
            for (int r = 0; r < 4; ++r) {
                int q = (w*2+qt2)*16 + quad*4 + r;
                ws[OFF_PO + (size_t)((c*4 + h)*256 + q)*32 + dtl*16 + l16] = o[qt2][dtl][r];
            }
        }
        #pragma unroll
        for (int r = 0; r < 4; ++r) {
            float v = lp[qt2][r];
            v += __shfl_xor(v, 1); v += __shfl_xor(v, 2);
            v += __shfl_xor(v, 4); v += __shfl_xor(v, 8);
            if (l16 == 0)
                ws[OFF_PL + (c*4 + h)*256 + (w*2+qt2)*16 + quad*4 + r] = v;
        }
    }
}

// ---------------------------------------------------------------- K4: merge + out proj + residual + LN
__global__ void __launch_bounds__(256) k4_out(
    const float* __restrict__ ws, const void* __restrict__ x,
    const void* __restrict__ outw, const void* __restrict__ lng,
    const void* __restrict__ lnb, void* __restrict__ outp)
{
    const bool f32 = ((const int*)ws)[0] != 0;
    int q = blockIdx.x, t = threadIdx.x;
    __shared__ float pl4[4][256];
    __shared__ float red[256];
    __shared__ float o2[128];
    __shared__ float stat[2];

    #pragma unroll
    for (int h = 0; h < 4; ++h)
        pl4[h][t] = (t < 64) ? ws[OFF_PL + (t*4 + h)*256 + q] : 0.f;
    __syncthreads();
    for (int s = 128; s > 0; s >>= 1) {
        if (t < s) {
            pl4[0][t] += pl4[0][t+s]; pl4[1][t] += pl4[1][t+s];
            pl4[2][t] += pl4[2][t+s]; pl4[3][t] += pl4[3][t+s];
        }
        __syncthreads();
    }
    int e = t & 127, h2 = e >> 5, d = e & 31, half = t >> 7;
    float a = 0.f;
    for (int mm = 0; mm < 32; ++mm) {
        int c = half*32 + mm;
        a += ws[OFF_PO + ((c*4 + h2)*256 + q)*32 + d];
    }
    red[t] = a;
    __syncthreads();
    if (t < 128) o2[t] = (red[t] + red[t+128]) / pl4[t>>5][0];
    __syncthreads();

    float rv = ldE(x, q*256 + t, f32);
    for (int i = 0; i < 16; ++i) {
        #pragma unroll
        for (int j = 0; j < 8; ++j) rv += o2[i*8+j]*ldE(outw, t*128 + i*8 + j, f32);
    }
    red[t] = rv; __syncthreads();
    for (int s = 128; s > 0; s >>= 1) { if (t < s) red[t] += red[t+s]; __syncthreads(); }
    if (t == 0) stat[0] = red[0] * (1.f/256.f);
    __syncthreads();
    float mu = stat[0];
    float dv = rv - mu;
    red[t] = dv*dv; __syncthreads();
    for (int s = 128; s > 0; s >>= 1) { if (t < s) red[t] += red[t+s]; __syncthreads(); }
    if (t == 0) stat[1] = red[0] * (1.f/256.f);
    __syncthreads();
    float rstd = rsqrtf(stat[1] + 1e-5f);
    float val = dv*rstd*ldE(lng,t,f32) + ldE(lnb,t,f32);
    if (f32) ((float*)outp)[q*256 + t] = val;
    else     ((bf16*)outp)[q*256 + t] = __float2bfloat16(val);
}

// ----------------------------------------------------------------
extern "C" void kernel_launch(void* const* d_in, const int* in_sizes, int n_in,
                              void* d_out, int out_size, void* d_ws, size_t ws_size,
                              hipStream_t stream)
{
    const void* x    = d_in[0];
    const void* y    = d_in[1];
    const void* xpos = d_in[2];
    const void* ypos = d_in[3];
    const void* thw  = d_in[4];
    const void* phiw = d_in[5];
    const void* gw   = d_in[6];
    const void* qw1  = d_in[7];
    const void* qb1  = d_in[8];
    const void* qw2  = d_in[9];
    const void* qb2  = d_in[10];
    const void* kw1  = d_in[11];
    const void* kb1  = d_in[12];
    const void* kw2  = d_in[13];
    const void* kb2  = d_in[14];
    const void* outw = d_in[15];
    const void* lng  = d_in[16];
    const void* lnb  = d_in[17];
    float* ws = (float*)d_ws;

    k_detect<<<1, 256, 0, stream>>>(x, (int*)d_ws);
    k0_prep<<<1281, 256, 0, stream>>>(x, y, xpos, ypos, thw, phiw, gw,
                                      qw1, qb1, qw2, qb2, kw1, kb1, kw2, kb2, ws);
    k1_gemm<<<16, 256, 0, stream>>>(ws);
    k2_gemm<<<4, 256, 0, stream>>>(ws);
    k3_attn<<<dim3(64, 4), 512, 0, stream>>>(ws);
    k4_out<<<256, 256, 0, stream>>>(ws, x, outw, lng, lnb, d_out);
}

// Round 5
// 203.753 us; speedup vs baseline: 2.8122x; 1.0087x over previous
//
#include <hip/hip_runtime.h>
#include <hip/hip_bf16.h>
#include <stdint.h>

// Problem: B=1, N=M=256, D=256, E=128, H=4, HD=32, P=64
typedef __hip_bfloat16 bf16;
typedef __attribute__((ext_vector_type(8))) short short8;
typedef __attribute__((ext_vector_type(4))) float f32x4;

__device__ __forceinline__ float b2f(bf16 v) { return __bfloat162float(v); }
__device__ __forceinline__ short f2bs(float f) {
    __hip_bfloat16 h = __float2bfloat16(f);
    return *reinterpret_cast<short*>(&h);
}
// flag-driven scalar load (inputs may be bf16 or f32)
__device__ __forceinline__ float ldE(const void* p, int i, bool f32) {
    return f32 ? ((const float*)p)[i] : b2f(((const bf16*)p)[i]);
}
// 8-element bf16 MFMA fragment from either dtype (idx must be 8-aligned)
__device__ __forceinline__ short8 ldfrag(const void* p, int idx, bool f32) {
    if (!f32) return *(const short8*)((const short*)p + idx);
    const float4* q = (const float4*)((const float*)p + idx);
    float4 a = q[0], b = q[1];
    short8 r;
    r[0]=f2bs(a.x); r[1]=f2bs(a.y); r[2]=f2bs(a.z); r[3]=f2bs(a.w);
    r[4]=f2bs(b.x); r[5]=f2bs(b.y); r[6]=f2bs(b.z); r[7]=f2bs(b.w);
    return r;
}
// per-block dtype detect: bf16 data -> low-half exponent field always in [96,160]
// (|x|~N(0,1)); f32 data -> those bits are mantissa noise, ~25% hit rate.
__device__ __forceinline__ bool detect_f32(const void* x) {
    const uint32_t* w = (const uint32_t*)x;
    uint32_t v = w[threadIdx.x & 63];
    uint32_t e = (v >> 7) & 0xffu;
    unsigned long long m = __ballot(e >= 96 && e <= 160);
    return __popcll(m) < 40;
}

// workspace layout (float offsets)
#define OFF_U     8         // [256][64]  u = x_pos@k_w1^T + k_b1           (f32)
#define OFF_W     16392     // [256][64]  w = y_pos@k_w1^T                  (f32)
#define OFF_QS    49416     // [256][128] q (scaled)                        (f32)
#define OFF_AX    82184     // [256][128] x @ phi_msg^T                     (f32)
#define OFF_AYP   114952    // [256][128] y @ phi_msg^T - phib              (f32)
#define OFF_GX    147720    // [256][128] x @ g_msg^T                       (f32)
#define OFF_GYP   180488    // [256][128] y @ g_msg^T - gb                  (f32)
#define OFF_PO    213256    // [64 c][4 h][256 q][32]  partial sum(exp*v)   (f32)
#define OFF_PL    2310408   // [64 c][4 h][256 q]      partial sum(exp)     (f32)
#define OFF_WPB   2375944   // [128][64]  bf16 phi_pe @ k_w2
#define OFF_WGB   2380040   // [128][64]  bf16 g_pe @ k_w2
// total < 9.6 MB

// ---------------------------------------------------------------- KA: all prep, one launch
// blocks [0,128): U/W  [128,192): WPB/WGB  [192,256): k1 GEMMs  [256,260): k2 GEMM
__global__ void __launch_bounds__(256) ka_prep(
    const void* __restrict__ x,    const void* __restrict__ y,
    const void* __restrict__ xpos, const void* __restrict__ ypos,
    const void* __restrict__ thw,  const void* __restrict__ phiw,
    const void* __restrict__ gw,
    const void* __restrict__ qw1,  const void* __restrict__ qb1,
    const void* __restrict__ qw2,  const void* __restrict__ qb2,
    const void* __restrict__ kw1,  const void* __restrict__ kb1,
    const void* __restrict__ kw2,  const void* __restrict__ kb2,
    float* __restrict__ ws)
{
    const bool f32 = detect_f32(x);
    const int b = blockIdx.x, t = threadIdx.x;
    __shared__ alignas(16) char smem[24576 + 512];

    if (b < 128) {                         // ---- U / W (elementwise)
        int id = b*256 + t;
        if (id < 16384) {
            int n = id >> 6, p = id & 63;
            ws[OFF_U + id] = ldE(kw1,p*3+0,f32)*ldE(xpos,n*3+0,f32)
                           + ldE(kw1,p*3+1,f32)*ldE(xpos,n*3+1,f32)
                           + ldE(kw1,p*3+2,f32)*ldE(xpos,n*3+2,f32) + ldE(kb1,p,f32);
        } else {
            int i = id - 16384; int m = i >> 6, p = i & 63;
            ws[OFF_W + i] = ldE(kw1,p*3+0,f32)*ldE(ypos,m*3+0,f32)
                          + ldE(kw1,p*3+1,f32)*ldE(ypos,m*3+1,f32)
                          + ldE(kw1,p*3+2,f32)*ldE(ypos,m*3+2,f32);
        }
    } else if (b < 192) {                  // ---- WPB / WGB (bf16)
        int id = (b-128)*256 + t;          // 0..16383
        const bool isP = (id < 8192);
        const void* src = isP ? phiw : gw;
        int i = isP ? id : id - 8192;
        int e = i >> 6, p = i & 63;
        float s = 0.f;
        for (int e2 = 0; e2 < 128; ++e2)
            s += ldE(src, e*384+256+e2, f32) * ldE(kw2, e2*64+p, f32);
        ((short*)(ws + (isP ? OFF_WPB : OFF_WGB)))[i] = f2bs(s);
    } else if (b < 256) {                  // ---- k1: Ax/AyP/Gx/GyP via MFMA
        const int bi = b - 192;
        const int which = bi >> 4, rg = bi & 15;
        const void* am = (which & 1) ? y : x;
        const void* wm = (which < 2) ? phiw : gw;
        float* sbias = (float*)smem;
        if (t < 128) {
            float s = 0.f;
            if (which & 1) {               // bias = pe-part @ k_b2 (folded into AyP/GyP)
                const void* pw = (which == 1) ? phiw : gw;
                for (int e2 = 0; e2 < 128; ++e2)
                    s += ldE(pw, t*384+256+e2, f32) * ldE(kb2, e2, f32);
            }
            sbias[t] = s;
        }
        __syncthreads();
        const int w = t >> 6, lane = t & 63, quad = lane >> 4, l16 = lane & 15;
        const int row0 = rg*16;
        f32x4 acc[2];
        #pragma unroll
        for (int c2 = 0; c2 < 2; ++c2) { acc[c2][0]=0.f; acc[c2][1]=0.f; acc[c2][2]=0.f; acc[c2][3]=0.f; }
        #pragma unroll 2
        for (int k = 0; k < 8; ++k) {
            short8 af = ldfrag(am, (row0 + l16)*256 + k*32 + quad*8, f32);
            #pragma unroll
            for (int c2 = 0; c2 < 2; ++c2) {
                int ct = w*2 + c2;
                short8 bf = ldfrag(wm, (ct*16 + l16)*384 + k*32 + quad*8, f32);
                acc[c2] = __builtin_amdgcn_mfma_f32_16x16x32_bf16(af, bf, acc[c2], 0, 0, 0);
            }
        }
        const int base = (which==0) ? OFF_AX : (which==1) ? OFF_AYP : (which==2) ? OFF_GX : OFF_GYP;
        #pragma unroll
        for (int c2 = 0; c2 < 2; ++c2) {
            int col = (w*2+c2)*16 + l16;
            #pragma unroll
            for (int r = 0; r < 4; ++r)
                ws[base + (row0 + quad*4 + r)*128 + col] = acc[c2][r] - sbias[col];
        }
    } else {                               // ---- k2: q = [x|qpe] @ theta^T via MFMA
        const int rg = b - 256;            // 0..3, 64 rows each
        const int w = t >> 6, lane = t & 63, quad = lane >> 4, l16 = lane & 15;
        const int row0 = rg*64;
        short* qpe_lds = (short*)smem;              // [64][128] bf16
        short* hq_lds  = (short*)(smem + 16384);    // [64][64]  bf16
        {   // hq = relu(xpos @ q_w1^T + q_b1)
            int row = t >> 2, p0 = (t & 3)*16;
            float px = ldE(xpos,(row0+row)*3+0,f32);
            float py = ldE(xpos,(row0+row)*3+1,f32);
            float pz = ldE(xpos,(row0+row)*3+2,f32);
            #pragma unroll
            for (int i = 0; i < 16; ++i) {
                int p = p0 + i;
                float v = ldE(qw1,p*3+0,f32)*px + ldE(qw1,p*3+1,f32)*py
                        + ldE(qw1,p*3+2,f32)*pz + ldE(qb1,p,f32);
                hq_lds[row*64 + p] = f2bs(fmaxf(v, 0.f));
            }
        }
        __syncthreads();
        {   // qpe = hq @ q_w2^T + q_b2  (wave w -> local rows w*16..+15)
            const short8 a0 = *(const short8*)(hq_lds + (w*16 + l16)*64 + quad*8);
            const short8 a1 = *(const short8*)(hq_lds + (w*16 + l16)*64 + 32 + quad*8);
            #pragma unroll
            for (int ct = 0; ct < 8; ++ct) {
                f32x4 acc; acc[0]=0.f; acc[1]=0.f; acc[2]=0.f; acc[3]=0.f;
                short8 b0 = ldfrag(qw2, (ct*16+l16)*64 + quad*8, f32);
                short8 b1 = ldfrag(qw2, (ct*16+l16)*64 + 32 + quad*8, f32);
                acc = __builtin_amdgcn_mfma_f32_16x16x32_bf16(a0, b0, acc, 0, 0, 0);
                acc = __builtin_amdgcn_mfma_f32_16x16x32_bf16(a1, b1, acc, 0, 0, 0);
                float qb = ldE(qb2, ct*16+l16, f32);
                #pragma unroll
                for (int r = 0; r < 4; ++r)
                    qpe_lds[(w*16 + quad*4 + r)*128 + ct*16 + l16] = f2bs(acc[r] + qb);
            }
        }
        __syncthreads();
        f32x4 acc[8];
        #pragma unroll
        for (int ct = 0; ct < 8; ++ct) { acc[ct][0]=0.f; acc[ct][1]=0.f; acc[ct][2]=0.f; acc[ct][3]=0.f; }
        for (int k = 0; k < 12; ++k) {
            const short8 af = (k < 8)
                ? ldfrag(x, (row0 + w*16 + l16)*256 + k*32 + quad*8, f32)
                : *(const short8*)(qpe_lds + (w*16 + l16)*128 + (k-8)*32 + quad*8);
            #pragma unroll
            for (int ct = 0; ct < 8; ++ct) {
                short8 bf = ldfrag(thw, (ct*16+l16)*384 + k*32 + quad*8, f32);
                acc[ct] = __builtin_amdgcn_mfma_f32_16x16x32_bf16(af, bf, acc[ct], 0, 0, 0);
            }
        }
        #pragma unroll
        for (int ct = 0; ct < 8; ++ct)
            #pragma unroll
            for (int r = 0; r < 4; ++r)
                ws[OFF_QS + (row0 + w*16 + quad*4 + r)*128 + ct*16 + l16] =
                    acc[ct][r] * 0.17677669529663687f;   // * HD^-0.5
    }
}

// ---------------------------------------------------------------- K3: MFMA k/v build + attention partials
// grid (c=64, h=4), 512 threads (8 waves). Block handles m = c*4..c*4+3.
// V and P use permuted within-32-chunk key order: col' = 2*(key&15) + ((key>>4)&1),
// making each lane's (e0,e1) pair adjacent -> packed b32 P-writes.
__global__ void __launch_bounds__(512) k3_attn(float* __restrict__ ws)
{
    const int c = blockIdx.x, h = blockIdx.y;
    const int tid = threadIdx.x;
    const int w = tid >> 6, lane = tid & 63;
    const int quad = lane >> 4, l16 = lane & 15;

    __shared__ float sW[64];
    __shared__ float sAy[32];
    __shared__ float sGy[32];
    __shared__ alignas(16) short s_hact[256*72];   // [key][p]  36 KB
    __shared__ alignas(16) short s_k[256*40];      // [key][d]  20 KB
    __shared__ alignas(16) short s_vt[32*264];     // [d][key'] 16.5 KB (permuted key order)
    __shared__ alignas(16) short s_p[8*2*16*40];   // per-(wave,qt) P tile, 20 KB

    short8 qa[2];
    #pragma unroll
    for (int qt2 = 0; qt2 < 2; ++qt2) {
        const float* qp = ws + OFF_QS + (size_t)((w*2+qt2)*16 + l16)*128 + h*32 + quad*8;
        short8 v;
        #pragma unroll
        for (int j = 0; j < 8; ++j) v[j] = f2bs(qp[j]);
        qa[qt2] = v;
    }

    f32x4 o[2][2];
    float lp[2][4];
    #pragma unroll
    for (int a = 0; a < 2; ++a) {
        #pragma unroll
        for (int d = 0; d < 2; ++d) { o[a][d][0]=0.f; o[a][d][1]=0.f; o[a][d][2]=0.f; o[a][d][3]=0.f; }
        #pragma unroll
        for (int r = 0; r < 4; ++r) lp[a][r] = 0.f;
    }

    const int which = w & 1, dtb = (w >> 1) & 1, ktg = w >> 2;
    const short* wbm = (const short*)(ws + (which ? OFF_WGB : OFF_WPB));
    const int ecol = h*32 + dtb*16 + l16;
    const short8 wb0 = *(const short8*)(wbm + ecol*64 + quad*8);
    const short8 wb1 = *(const short8*)(wbm + ecol*64 + 32 + quad*8);
    const float* xb = ws + (which ? OFF_GX : OFF_AX);

    for (int mi = 0; mi < 4; ++mi) {
        const int m = c*4 + mi;
        __syncthreads();
        if (tid < 64)       sW[tid]      = ws[OFF_W + m*64 + tid];
        else if (tid < 96)  sAy[tid-64]  = ws[OFF_AYP + m*128 + h*32 + (tid-64)];
        else if (tid < 128) sGy[tid-96]  = ws[OFF_GYP + m*128 + h*32 + (tid-96)];
        __syncthreads();

        {   // hact[key][p] = relu(u[key][p] - w[m][p])
            const int key = tid >> 1, half = tid & 1;
            const float4* up = (const float4*)(ws + OFF_U + key*64 + half*32);
            short* hd = s_hact + key*72 + half*32;
            #pragma unroll
            for (int i = 0; i < 8; ++i) {
                float4 u4 = up[i]; int p = half*32 + i*4;
                hd[i*4+0] = f2bs(fmaxf(u4.x - sW[p+0], 0.f));
                hd[i*4+1] = f2bs(fmaxf(u4.y - sW[p+1], 0.f));
                hd[i*4+2] = f2bs(fmaxf(u4.z - sW[p+2], 0.f));
                hd[i*4+3] = f2bs(fmaxf(u4.w - sW[p+3], 0.f));
            }
        }
        __syncthreads();

        {   // K/V build via MFMA
            const float ycol = (which ? sGy : sAy)[dtb*16 + l16];
            #pragma unroll 2
            for (int i = 0; i < 8; ++i) {
                const int kt = ktg*8 + i;
                f32x4 acc;
                #pragma unroll
                for (int r = 0; r < 4; ++r)
                    acc[r] = xb[(size_t)(kt*16 + quad*4 + r)*128 + ecol] - ycol;
                const short8 a0 = *(const short8*)(s_hact + (kt*16 + l16)*72 + quad*8);
                const short8 a1 = *(const short8*)(s_hact + (kt*16 + l16)*72 + 32 + quad*8);
                acc = __builtin_amdgcn_mfma_f32_16x16x32_bf16(a0, wb0, acc, 0, 0, 0);
                acc = __builtin_amdgcn_mfma_f32_16x16x32_bf16(a1, wb1, acc, 0, 0, 0);
                if (which == 0) {
                    #pragma unroll
                    for (int r = 0; r < 4; ++r)
                        s_k[(kt*16 + quad*4 + r)*40 + dtb*16 + l16] = f2bs(acc[r]);
                } else {
                    // permuted key position within chunk
                    const int kp = (kt >> 1)*32 + ((quad*4)<<1) + (kt & 1);
                    #pragma unroll
                    for (int r = 0; r < 4; ++r)
                        s_vt[(dtb*16 + l16)*264 + kp + (r<<1)] = f2bs(acc[r]);
                }
            }
        }
        __syncthreads();

        // attention: per 32-key chunk: scores -> exp -> P(LDS, packed) -> PV
        for (int kc = 0; kc < 8; ++kc) {
            const short8 kb0 = *(const short8*)(s_k + (kc*32 + l16)*40 + quad*8);
            const short8 kb1 = *(const short8*)(s_k + (kc*32 + 16 + l16)*40 + quad*8);
            const short8 vb0 = *(const short8*)(s_vt + l16*264 + kc*32 + quad*8);
            const short8 vb1 = *(const short8*)(s_vt + (16 + l16)*264 + kc*32 + quad*8);
            #pragma unroll
            for (int qt2 = 0; qt2 < 2; ++qt2) {
                f32x4 z; z[0]=0.f; z[1]=0.f; z[2]=0.f; z[3]=0.f;
                f32x4 s0 = __builtin_amdgcn_mfma_f32_16x16x32_bf16(qa[qt2], kb0, z, 0, 0, 0);
                f32x4 s1 = __builtin_amdgcn_mfma_f32_16x16x32_bf16(qa[qt2], kb1, z, 0, 0, 0);
                short* pb = s_p + (w*2 + qt2)*640;
                #pragma unroll
                for (int r = 0; r < 4; ++r) {
                    float e0 = __expf(s0[r]);      // key kc*32+l16      -> col 2*l16
                    float e1 = __expf(s1[r]);      // key kc*32+16+l16   -> col 2*l16+1
                    lp[qt2][r] += e0 + e1;
                    uint32_t pk = (uint32_t)(uint16_t)f2bs(e0)
                                | ((uint32_t)(uint16_t)f2bs(e1) << 16);
                    *(uint32_t*)(pb + (quad*4+r)*40 + 2*l16) = pk;
                }
                const short8 pa = *(const short8*)(pb + l16*40 + quad*8);
                o[qt2][0] = __builtin_amdgcn_mfma_f32_16x16x32_bf16(pa, vb0, o[qt2][0], 0, 0, 0);
                o[qt2][1] = __builtin_amdgcn_mfma_f32_16x16x32_bf16(pa, vb1, o[qt2][1], 0, 0, 0);
            }
        }
    }

    #pragma unroll
    for (int qt2 = 0; qt2 < 2; ++qt2) {
        #pragma unroll
        for (int dtl = 0; dtl < 2; ++dtl) {
            #pragma unroll
            for (int r = 0; r < 4; ++r) {
                int q = (w*2+qt2)*16 + quad*4 + r;
                ws[OFF_PO + (size_t)((c*4 + h)*256 + q)*32 + dtl*16 + l16] = o[qt2][dtl][r];
            }
        }
        #pragma unroll
        for (int r = 0; r < 4; ++r) {
            float v = lp[qt2][r];
            v += __shfl_xor(v, 1); v += __shfl_xor(v, 2);
            v += __shfl_xor(v, 4); v += __shfl_xor(v, 8);
            if (l16 == 0)
                ws[OFF_PL + (c*4 + h)*256 + (w*2+qt2)*16 + quad*4 + r] = v;
        }
    }
}

// ---------------------------------------------------------------- K4: merge + out proj + residual + LN
__global__ void __launch_bounds__(256) k4_out(
    const float* __restrict__ ws, const void* __restrict__ x,
    const void* __restrict__ outw, const void* __restrict__ lng,
    const void* __restrict__ lnb, void* __restrict__ outp)
{
    const bool f32 = detect_f32(x);
    int q = blockIdx.x, t = threadIdx.x;
    __shared__ float pl4[4][256];
    __shared__ float red[256];
    __shared__ float o2[128];
    __shared__ float stat[2];

    #pragma unroll
    for (int h = 0; h < 4; ++h)
        pl4[h][t] = (t < 64) ? ws[OFF_PL + (t*4 + h)*256 + q] : 0.f;
    __syncthreads();
    for (int s = 128; s > 0; s >>= 1) {
        if (t < s) {
            pl4[0][t] += pl4[0][t+s]; pl4[1][t] += pl4[1][t+s];
            pl4[2][t] += pl4[2][t+s]; pl4[3][t] += pl4[3][t+s];
        }
        __syncthreads();
    }
    int e = t & 127, h2 = e >> 5, d = e & 31, half = t >> 7;
    float a = 0.f;
    for (int mm = 0; mm < 32; ++mm) {
        int c = half*32 + mm;
        a += ws[OFF_PO + ((c*4 + h2)*256 + q)*32 + d];
    }
    red[t] = a;
    __syncthreads();
    if (t < 128) o2[t] = (red[t] + red[t+128]) / pl4[t>>5][0];
    __syncthreads();

    float rv = ldE(x, q*256 + t, f32);
    for (int i = 0; i < 16; ++i) {
        #pragma unroll
        for (int j = 0; j < 8; ++j) rv += o2[i*8+j]*ldE(outw, t*128 + i*8 + j, f32);
    }
    red[t] = rv; __syncthreads();
    for (int s = 128; s > 0; s >>= 1) { if (t < s) red[t] += red[t+s]; __syncthreads(); }
    if (t == 0) stat[0] = red[0] * (1.f/256.f);
    __syncthreads();
    float mu = stat[0];
    float dv = rv - mu;
    red[t] = dv*dv; __syncthreads();
    for (int s = 128; s > 0; s >>= 1) { if (t < s) red[t] += red[t+s]; __syncthreads(); }
    if (t == 0) stat[1] = red[0] * (1.f/256.f);
    __syncthreads();
    float rstd = rsqrtf(stat[1] + 1e-5f);
    float val = dv*rstd*ldE(lng,t,f32) + ldE(lnb,t,f32);
    if (f32) ((float*)outp)[q*256 + t] = val;
    else     ((bf16*)outp)[q*256 + t] = __float2bfloat16(val);
}

// ----------------------------------------------------------------
extern "C" void kernel_launch(void* const* d_in, const int* in_sizes, int n_in,
                              void* d_out, int out_size, void* d_ws, size_t ws_size,
                              hipStream_t stream)
{
    const void* x    = d_in[0];
    const void* y    = d_in[1];
    const void* xpos = d_in[2];
    const void* ypos = d_in[3];
    const void* thw  = d_in[4];
    const void* phiw = d_in[5];
    const void* gw   = d_in[6];
    const void* qw1  = d_in[7];
    const void* qb1  = d_in[8];
    const void* qw2  = d_in[9];
    const void* qb2  = d_in[10];
    const void* kw1  = d_in[11];
    const void* kb1  = d_in[12];
    const void* kw2  = d_in[13];
    const void* kb2  = d_in[14];
    const void* outw = d_in[15];
    const void* lng  = d_in[16];
    const void* lnb  = d_in[17];
    float* ws = (float*)d_ws;

    ka_prep<<<260, 256, 0, stream>>>(x, y, xpos, ypos, thw, phiw, gw,
                                     qw1, qb1, qw2, qb2, kw1, kb1, kw2, kb2, ws);
    k3_attn<<<dim3(64, 4), 512, 0, stream>>>(ws);
    k4_out<<<256, 256, 0, stream>>>(ws, x, outw, lng, lnb, d_out);
}

// Round 6
// 195.246 us; speedup vs baseline: 2.9347x; 1.0436x over previous
//
#include <hip/hip_runtime.h>
#include <hip/hip_bf16.h>
#include <stdint.h>

// Problem: B=1, N=M=256, D=256, E=128, H=4, HD=32, P=64
typedef __hip_bfloat16 bf16;
typedef __attribute__((ext_vector_type(8))) short short8;
typedef __attribute__((ext_vector_type(4))) float f32x4;

__device__ __forceinline__ float b2f(bf16 v) { return __bfloat162float(v); }
__device__ __forceinline__ short f2bs(float f) {
    __hip_bfloat16 h = __float2bfloat16(f);
    return *reinterpret_cast<short*>(&h);
}
__device__ __forceinline__ float bs2f(short s) {
    union { uint32_t u; float f; } c; c.u = ((uint32_t)(uint16_t)s) << 16; return c.f;
}
// flag-driven scalar load (inputs may be bf16 or f32)
__device__ __forceinline__ float ldE(const void* p, int i, bool f32) {
    return f32 ? ((const float*)p)[i] : b2f(((const bf16*)p)[i]);
}
// 8-element bf16 MFMA fragment from either dtype (idx must be 8-aligned)
__device__ __forceinline__ short8 ldfrag(const void* p, int idx, bool f32) {
    if (!f32) return *(const short8*)((const short*)p + idx);
    const float4* q = (const float4*)((const float*)p + idx);
    float4 a = q[0], b = q[1];
    short8 r;
    r[0]=f2bs(a.x); r[1]=f2bs(a.y); r[2]=f2bs(a.z); r[3]=f2bs(a.w);
    r[4]=f2bs(b.x); r[5]=f2bs(b.y); r[6]=f2bs(b.z); r[7]=f2bs(b.w);
    return r;
}
// per-block dtype detect: bf16 data -> low-half exponent field in [96,160]
__device__ __forceinline__ bool detect_f32(const void* x) {
    const uint32_t* w = (const uint32_t*)x;
    uint32_t v = w[threadIdx.x & 63];
    uint32_t e = (v >> 7) & 0xffu;
    unsigned long long m = __ballot(e >= 96 && e <= 160);
    return __popcll(m) < 40;
}

// workspace layout (float offsets)
#define OFF_U     8         // [256][64]  u = x_pos@k_w1^T + k_b1           (f32)
#define OFF_W     16392     // [256][64]  w = y_pos@k_w1^T                  (f32)
#define OFF_QS    49416     // [256][128] q (scaled)                        (f32)
#define OFF_AX    82184     // [256][128] x @ phi_msg^T                     (f32)
#define OFF_AYP   114952    // [256][128] y @ phi_msg^T - phib              (f32)
#define OFF_GX    147720    // [256][128] x @ g_msg^T                       (f32)
#define OFF_GYP   180488    // [256][128] y @ g_msg^T - gb                  (f32)
#define OFF_PO    213256    // [64 c][4 h][256 q][32]  partial sum(exp*v)   (f32)
#define OFF_PL    2310408   // [64 c][4 h][256 q]      partial sum(exp)     (f32)
#define OFF_WPB   2375944   // [128][64]  bf16 phi_pe @ k_w2
#define OFF_WGB   2380040   // [128][64]  bf16 g_pe @ k_w2
// total < 9.6 MB

// ---------------------------------------------------------------- KA: all prep, one launch
// blocks [0,128): U/W  [128,192): WPB/WGB  [192,256): k1 GEMMs  [256,260): k2 GEMM
__global__ void __launch_bounds__(256) ka_prep(
    const void* __restrict__ x,    const void* __restrict__ y,
    const void* __restrict__ xpos, const void* __restrict__ ypos,
    const void* __restrict__ thw,  const void* __restrict__ phiw,
    const void* __restrict__ gw,
    const void* __restrict__ qw1,  const void* __restrict__ qb1,
    const void* __restrict__ qw2,  const void* __restrict__ qb2,
    const void* __restrict__ kw1,  const void* __restrict__ kb1,
    const void* __restrict__ kw2,  const void* __restrict__ kb2,
    float* __restrict__ ws)
{
    const bool f32 = detect_f32(x);
    const int b = blockIdx.x, t = threadIdx.x;
    __shared__ alignas(16) char smem[24576 + 512];

    if (b < 128) {                         // ---- U / W (elementwise)
        int id = b*256 + t;
        if (id < 16384) {
            int n = id >> 6, p = id & 63;
            ws[OFF_U + id] = ldE(kw1,p*3+0,f32)*ldE(xpos,n*3+0,f32)
                           + ldE(kw1,p*3+1,f32)*ldE(xpos,n*3+1,f32)
                           + ldE(kw1,p*3+2,f32)*ldE(xpos,n*3+2,f32) + ldE(kb1,p,f32);
        } else {
            int i = id - 16384; int m = i >> 6, p = i & 63;
            ws[OFF_W + i] = ldE(kw1,p*3+0,f32)*ldE(ypos,m*3+0,f32)
                          + ldE(kw1,p*3+1,f32)*ldE(ypos,m*3+1,f32)
                          + ldE(kw1,p*3+2,f32)*ldE(ypos,m*3+2,f32);
        }
    } else if (b < 192) {                  // ---- WPB / WGB (bf16), fully unrolled
        int id = (b-128)*256 + t;          // 0..16383
        const bool isP = (id < 8192);
        const void* src = isP ? phiw : gw;
        int i = isP ? id : id - 8192;
        int e = i >> 6, p = i & 63;        // e wave-uniform, p = lane -> kw2 coalesced
        float s = 0.f;
        #pragma unroll
        for (int k = 0; k < 16; ++k) {
            short8 a = ldfrag(src, e*384 + 256 + k*8, f32);   // broadcast row segment
            #pragma unroll
            for (int j = 0; j < 8; ++j)
                s += bs2f(a[j]) * ldE(kw2, (k*8+j)*64 + p, f32);
        }
        ((short*)(ws + (isP ? OFF_WPB : OFF_WGB)))[i] = f2bs(s);
    } else if (b < 256) {                  // ---- k1: Ax/AyP/Gx/GyP via MFMA
        const int bi = b - 192;
        const int which = bi >> 4, rg = bi & 15;
        const void* am = (which & 1) ? y : x;
        const void* wm = (which < 2) ? phiw : gw;
        float* sbias = (float*)smem;
        if (t < 128) {
            float s = 0.f;
            if (which & 1) {               // bias = pe-part @ k_b2 (folded into AyP/GyP)
                const void* pw = (which == 1) ? phiw : gw;
                #pragma unroll
                for (int k = 0; k < 16; ++k) {
                    short8 a  = ldfrag(pw,  t*384 + 256 + k*8, f32);
                    short8 bb = ldfrag(kb2, k*8, f32);
                    #pragma unroll
                    for (int j = 0; j < 8; ++j) s += bs2f(a[j]) * bs2f(bb[j]);
                }
            }
            sbias[t] = s;
        }
        __syncthreads();
        const int w = t >> 6, lane = t & 63, quad = lane >> 4, l16 = lane & 15;
        const int row0 = rg*16;
        f32x4 acc[2];
        #pragma unroll
        for (int c2 = 0; c2 < 2; ++c2) { acc[c2][0]=0.f; acc[c2][1]=0.f; acc[c2][2]=0.f; acc[c2][3]=0.f; }
        #pragma unroll 2
        for (int k = 0; k < 8; ++k) {
            short8 af = ldfrag(am, (row0 + l16)*256 + k*32 + quad*8, f32);
            #pragma unroll
            for (int c2 = 0; c2 < 2; ++c2) {
                int ct = w*2 + c2;
                short8 bf = ldfrag(wm, (ct*16 + l16)*384 + k*32 + quad*8, f32);
                acc[c2] = __builtin_amdgcn_mfma_f32_16x16x32_bf16(af, bf, acc[c2], 0, 0, 0);
            }
        }
        const int base = (which==0) ? OFF_AX : (which==1) ? OFF_AYP : (which==2) ? OFF_GX : OFF_GYP;
        #pragma unroll
        for (int c2 = 0; c2 < 2; ++c2) {
            int col = (w*2+c2)*16 + l16;
            #pragma unroll
            for (int r = 0; r < 4; ++r)
                ws[base + (row0 + quad*4 + r)*128 + col] = acc[c2][r] - sbias[col];
        }
    } else {                               // ---- k2: q = [x|qpe] @ theta^T via MFMA
        const int rg = b - 256;            // 0..3, 64 rows each
        const int w = t >> 6, lane = t & 63, quad = lane >> 4, l16 = lane & 15;
        const int row0 = rg*64;
        short* qpe_lds = (short*)smem;              // [64][128] bf16
        short* hq_lds  = (short*)(smem + 16384);    // [64][64]  bf16
        {   // hq = relu(xpos @ q_w1^T + q_b1)
            int row = t >> 2, p0 = (t & 3)*16;
            float px = ldE(xpos,(row0+row)*3+0,f32);
            float py = ldE(xpos,(row0+row)*3+1,f32);
            float pz = ldE(xpos,(row0+row)*3+2,f32);
            #pragma unroll
            for (int i = 0; i < 16; ++i) {
                int p = p0 + i;
                float v = ldE(qw1,p*3+0,f32)*px + ldE(qw1,p*3+1,f32)*py
                        + ldE(qw1,p*3+2,f32)*pz + ldE(qb1,p,f32);
                hq_lds[row*64 + p] = f2bs(fmaxf(v, 0.f));
            }
        }
        __syncthreads();
        {   // qpe = hq @ q_w2^T + q_b2
            const short8 a0 = *(const short8*)(hq_lds + (w*16 + l16)*64 + quad*8);
            const short8 a1 = *(const short8*)(hq_lds + (w*16 + l16)*64 + 32 + quad*8);
            #pragma unroll
            for (int ct = 0; ct < 8; ++ct) {
                f32x4 acc; acc[0]=0.f; acc[1]=0.f; acc[2]=0.f; acc[3]=0.f;
                short8 b0 = ldfrag(qw2, (ct*16+l16)*64 + quad*8, f32);
                short8 b1 = ldfrag(qw2, (ct*16+l16)*64 + 32 + quad*8, f32);
                acc = __builtin_amdgcn_mfma_f32_16x16x32_bf16(a0, b0, acc, 0, 0, 0);
                acc = __builtin_amdgcn_mfma_f32_16x16x32_bf16(a1, b1, acc, 0, 0, 0);
                float qb = ldE(qb2, ct*16+l16, f32);
                #pragma unroll
                for (int r = 0; r < 4; ++r)
                    qpe_lds[(w*16 + quad*4 + r)*128 + ct*16 + l16] = f2bs(acc[r] + qb);
            }
        }
        __syncthreads();
        f32x4 acc[8];
        #pragma unroll
        for (int ct = 0; ct < 8; ++ct) { acc[ct][0]=0.f; acc[ct][1]=0.f; acc[ct][2]=0.f; acc[ct][3]=0.f; }
        for (int k = 0; k < 12; ++k) {
            const short8 af = (k < 8)
                ? ldfrag(x, (row0 + w*16 + l16)*256 + k*32 + quad*8, f32)
                : *(const short8*)(qpe_lds + (w*16 + l16)*128 + (k-8)*32 + quad*8);
            #pragma unroll
            for (int ct = 0; ct < 8; ++ct) {
                short8 bf = ldfrag(thw, (ct*16+l16)*384 + k*32 + quad*8, f32);
                acc[ct] = __builtin_amdgcn_mfma_f32_16x16x32_bf16(af, bf, acc[ct], 0, 0, 0);
            }
        }
        #pragma unroll
        for (int ct = 0; ct < 8; ++ct)
            #pragma unroll
            for (int r = 0; r < 4; ++r)
                ws[OFF_QS + (row0 + w*16 + quad*4 + r)*128 + ct*16 + l16] =
                    acc[ct][r] * 0.17677669529663687f;   // * HD^-0.5
    }
}

// ---------------------------------------------------------------- K3: MFMA k/v build + attention partials
// grid (c=64, h=4, qh=2), 512 threads (8 waves), 2 blocks/CU. Block: m = c*4..c*4+3,
// queries qh*128..+127 (wave w owns q-tile q0 = qh*128 + w*16).
// s_p aliases s_hact (phases sync-separated) -> ~75 KB LDS.
__global__ void __launch_bounds__(512, 4) k3_attn(float* __restrict__ ws)
{
    const int c = blockIdx.x, h = blockIdx.y, qh = blockIdx.z;
    const int tid = threadIdx.x;
    const int w = tid >> 6, lane = tid & 63;
    const int quad = lane >> 4, l16 = lane & 15;

    __shared__ float sW[64];
    __shared__ float sAy[32];
    __shared__ float sGy[32];
    __shared__ alignas(16) short s_hact[256*72];   // 36 KB (attn phase: aliased by s_p)
    __shared__ alignas(16) short s_k[256*40];      // 20 KB
    __shared__ alignas(16) short s_vt[32*264];     // 16.5 KB (permuted key order)
    short* const s_p = s_hact;                     // alias: 8 waves x 640 shorts = 10 KB

    const int q0 = qh*128 + w*16;
    short8 qa;
    {
        const float* qp = ws + OFF_QS + (size_t)(q0 + l16)*128 + h*32 + quad*8;
        #pragma unroll
        for (int j = 0; j < 8; ++j) qa[j] = f2bs(qp[j]);
    }

    f32x4 o[2];
    float lp[4];
    #pragma unroll
    for (int d = 0; d < 2; ++d) { o[d][0]=0.f; o[d][1]=0.f; o[d][2]=0.f; o[d][3]=0.f; }
    #pragma unroll
    for (int r = 0; r < 4; ++r) lp[r] = 0.f;

    const int which = w & 1, dtb = (w >> 1) & 1, ktg = w >> 2;
    const short* wbm = (const short*)(ws + (which ? OFF_WGB : OFF_WPB));
    const int ecol = h*32 + dtb*16 + l16;
    const short8 wb0 = *(const short8*)(wbm + ecol*64 + quad*8);
    const short8 wb1 = *(const short8*)(wbm + ecol*64 + 32 + quad*8);
    const float* xb = ws + (which ? OFF_GX : OFF_AX);

    for (int mi = 0; mi < 4; ++mi) {
        const int m = c*4 + mi;
        __syncthreads();   // prior attn (s_p in hact region) done before hact rewrite
        if (tid < 64)       sW[tid]      = ws[OFF_W + m*64 + tid];
        else if (tid < 96)  sAy[tid-64]  = ws[OFF_AYP + m*128 + h*32 + (tid-64)];
        else if (tid < 128) sGy[tid-96]  = ws[OFF_GYP + m*128 + h*32 + (tid-96)];
        __syncthreads();

        {   // hact[key][p] = relu(u[key][p] - w[m][p])
            const int key = tid >> 1, half = tid & 1;
            const float4* up = (const float4*)(ws + OFF_U + key*64 + half*32);
            short* hd = s_hact + key*72 + half*32;
            #pragma unroll
            for (int i = 0; i < 8; ++i) {
                float4 u4 = up[i]; int p = half*32 + i*4;
                hd[i*4+0] = f2bs(fmaxf(u4.x - sW[p+0], 0.f));
                hd[i*4+1] = f2bs(fmaxf(u4.y - sW[p+1], 0.f));
                hd[i*4+2] = f2bs(fmaxf(u4.z - sW[p+2], 0.f));
                hd[i*4+3] = f2bs(fmaxf(u4.w - sW[p+3], 0.f));
            }
        }
        __syncthreads();

        {   // K/V build via MFMA
            const float ycol = (which ? sGy : sAy)[dtb*16 + l16];
            #pragma unroll 2
            for (int i = 0; i < 8; ++i) {
                const int kt = ktg*8 + i;
                f32x4 acc;
                #pragma unroll
                for (int r = 0; r < 4; ++r)
                    acc[r] = xb[(size_t)(kt*16 + quad*4 + r)*128 + ecol] - ycol;
                const short8 a0 = *(const short8*)(s_hact + (kt*16 + l16)*72 + quad*8);
                const short8 a1 = *(const short8*)(s_hact + (kt*16 + l16)*72 + 32 + quad*8);
                acc = __builtin_amdgcn_mfma_f32_16x16x32_bf16(a0, wb0, acc, 0, 0, 0);
                acc = __builtin_amdgcn_mfma_f32_16x16x32_bf16(a1, wb1, acc, 0, 0, 0);
                if (which == 0) {
                    #pragma unroll
                    for (int r = 0; r < 4; ++r)
                        s_k[(kt*16 + quad*4 + r)*40 + dtb*16 + l16] = f2bs(acc[r]);
                } else {
                    const int kp = (kt >> 1)*32 + ((quad*4)<<1) + (kt & 1);  // permuted col
                    #pragma unroll
                    for (int r = 0; r < 4; ++r)
                        s_vt[(dtb*16 + l16)*264 + kp + (r<<1)] = f2bs(acc[r]);
                }
            }
        }
        __syncthreads();

        // attention: per 32-key chunk: scores -> exp -> P(LDS, packed) -> PV
        for (int kc = 0; kc < 8; ++kc) {
            const short8 kb0 = *(const short8*)(s_k + (kc*32 + l16)*40 + quad*8);
            const short8 kb1 = *(const short8*)(s_k + (kc*32 + 16 + l16)*40 + quad*8);
            const short8 vb0 = *(const short8*)(s_vt + l16*264 + kc*32 + quad*8);
            const short8 vb1 = *(const short8*)(s_vt + (16 + l16)*264 + kc*32 + quad*8);
            f32x4 z; z[0]=0.f; z[1]=0.f; z[2]=0.f; z[3]=0.f;
            f32x4 s0 = __builtin_amdgcn_mfma_f32_16x16x32_bf16(qa, kb0, z, 0, 0, 0);
            f32x4 s1 = __builtin_amdgcn_mfma_f32_16x16x32_bf16(qa, kb1, z, 0, 0, 0);
            short* pb = s_p + w*640;
            #pragma unroll
            for (int r = 0; r < 4; ++r) {
                float e0 = __expf(s0[r]);      // key kc*32+l16    -> col 2*l16
                float e1 = __expf(s1[r]);      // key kc*32+16+l16 -> col 2*l16+1
                lp[r] += e0 + e1;
                uint32_t pk = (uint32_t)(uint16_t)f2bs(e0)
                            | ((uint32_t)(uint16_t)f2bs(e1) << 16);
                *(uint32_t*)(pb + (quad*4+r)*40 + 2*l16) = pk;
            }
            const short8 pa = *(const short8*)(pb + l16*40 + quad*8);
            o[0] = __builtin_amdgcn_mfma_f32_16x16x32_bf16(pa, vb0, o[0], 0, 0, 0);
            o[1] = __builtin_amdgcn_mfma_f32_16x16x32_bf16(pa, vb1, o[1], 0, 0, 0);
        }
    }

    #pragma unroll
    for (int dtl = 0; dtl < 2; ++dtl)
        #pragma unroll
        for (int r = 0; r < 4; ++r)
            ws[OFF_PO + (size_t)((c*4 + h)*256 + q0 + quad*4 + r)*32 + dtl*16 + l16] = o[dtl][r];
    #pragma unroll
    for (int r = 0; r < 4; ++r) {
        float v = lp[r];
        v += __shfl_xor(v, 1); v += __shfl_xor(v, 2);
        v += __shfl_xor(v, 4); v += __shfl_xor(v, 8);
        if (l16 == 0)
            ws[OFF_PL + (c*4 + h)*256 + q0 + quad*4 + r] = v;
    }
}

// ---------------------------------------------------------------- K4: merge + out proj + residual + LN
__global__ void __launch_bounds__(256) k4_out(
    const float* __restrict__ ws, const void* __restrict__ x,
    const void* __restrict__ outw, const void* __restrict__ lng,
    const void* __restrict__ lnb, void* __restrict__ outp)
{
    const bool f32 = detect_f32(x);
    int q = blockIdx.x, t = threadIdx.x;
    __shared__ float pl4[4][256];
    __shared__ float red[256];
    __shared__ float o2[128];
    __shared__ float stat[2];

    #pragma unroll
    for (int h = 0; h < 4; ++h)
        pl4[h][t] = (t < 64) ? ws[OFF_PL + (t*4 + h)*256 + q] : 0.f;
    __syncthreads();
    for (int s = 128; s > 0; s >>= 1) {
        if (t < s) {
            pl4[0][t] += pl4[0][t+s]; pl4[1][t] += pl4[1][t+s];
            pl4[2][t] += pl4[2][t+s]; pl4[3][t] += pl4[3][t+s];
        }
        __syncthreads();
    }
    int e = t & 127, h2 = e >> 5, d = e & 31, half = t >> 7;
    float a = 0.f;
    #pragma unroll
    for (int mm = 0; mm < 32; ++mm) {
        int c = half*32 + mm;
        a += ws[OFF_PO + ((c*4 + h2)*256 + q)*32 + d];
    }
    red[t] = a;
    __syncthreads();
    if (t < 128) o2[t] = (red[t] + red[t+128]) / pl4[t>>5][0];
    __syncthreads();

    float rv = ldE(x, q*256 + t, f32);
    #pragma unroll
    for (int i = 0; i < 16; ++i) {
        short8 wv = ldfrag(outw, t*128 + i*8, f32);
        #pragma unroll
        for (int j = 0; j < 8; ++j) rv += o2[i*8+j]*bs2f(wv[j]);
    }
    red[t] = rv; __syncthreads();
    for (int s = 128; s > 0; s >>= 1) { if (t < s) red[t] += red[t+s]; __syncthreads(); }
    if (t == 0) stat[0] = red[0] * (1.f/256.f);
    __syncthreads();
    float mu = stat[0];
    float dv = rv - mu;
    red[t] = dv*dv; __syncthreads();
    for (int s = 128; s > 0; s >>= 1) { if (t < s) red[t] += red[t+s]; __syncthreads(); }
    if (t == 0) stat[1] = red[0] * (1.f/256.f);
    __syncthreads();
    float rstd = rsqrtf(stat[1] + 1e-5f);
    float val = dv*rstd*ldE(lng,t,f32) + ldE(lnb,t,f32);
    if (f32) ((float*)outp)[q*256 + t] = val;
    else     ((bf16*)outp)[q*256 + t] = __float2bfloat16(val);
}

// ----------------------------------------------------------------
extern "C" void kernel_launch(void* const* d_in, const int* in_sizes, int n_in,
                              void* d_out, int out_size, void* d_ws, size_t ws_size,
                              hipStream_t stream)
{
    const void* x    = d_in[0];
    const void* y    = d_in[1];
    const void* xpos = d_in[2];
    const void* ypos = d_in[3];
    const void* thw  = d_in[4];
    const void* phiw = d_in[5];
    const void* gw   = d_in[6];
    const void* qw1  = d_in[7];
    const void* qb1  = d_in[8];
    const void* qw2  = d_in[9];
    const void* qb2  = d_in[10];
    const void* kw1  = d_in[11];
    const void* kb1  = d_in[12];
    const void* kw2  = d_in[13];
    const void* kb2  = d_in[14];
    const void* outw = d_in[15];
    const void* lng  = d_in[16];
    const void* lnb  = d_in[17];
    float* ws = (float*)d_ws;

    ka_prep<<<260, 256, 0, stream>>>(x, y, xpos, ypos, thw, phiw, gw,
                                     qw1, qb1, qw2, qb2, kw1, kb1, kw2, kb2, ws);
    k3_attn<<<dim3(64, 4, 2), 512, 0, stream>>>(ws);
    k4_out<<<256, 256, 0, stream>>>(ws, x, outw, lng, lnb, d_out);
}

// Round 8
// 189.108 us; speedup vs baseline: 3.0300x; 1.0325x over previous
//
#include <hip/hip_runtime.h>
#include <hip/hip_bf16.h>
#include <stdint.h>

// Problem: B=1, N=M=256, D=256, E=128, H=4, HD=32, P=64
typedef __hip_bfloat16 bf16;
typedef __attribute__((ext_vector_type(8))) short short8;
typedef __attribute__((ext_vector_type(4))) float f32x4;

__device__ __forceinline__ float b2f(bf16 v) { return __bfloat162float(v); }
__device__ __forceinline__ short f2bs(float f) {
    __hip_bfloat16 h = __float2bfloat16(f);
    return *reinterpret_cast<short*>(&h);
}
__device__ __forceinline__ float bs2f(short s) {
    union { uint32_t u; float f; } c; c.u = ((uint32_t)(uint16_t)s) << 16; return c.f;
}
// compile-time dtype loads (branch hoisted to kernel top)
template<bool F32> __device__ __forceinline__ float ldT(const void* p, int i) {
    if constexpr (F32) return ((const float*)p)[i];
    else               return b2f(((const bf16*)p)[i]);
}
template<bool F32> __device__ __forceinline__ short8 ldfragT(const void* p, int idx) {
    if constexpr (F32) {
        const float4* q = (const float4*)((const float*)p + idx);
        float4 a = q[0], b = q[1];
        short8 r;
        r[0]=f2bs(a.x); r[1]=f2bs(a.y); r[2]=f2bs(a.z); r[3]=f2bs(a.w);
        r[4]=f2bs(b.x); r[5]=f2bs(b.y); r[6]=f2bs(b.z); r[7]=f2bs(b.w);
        return r;
    } else {
        return *(const short8*)((const short*)p + idx);
    }
}
// per-block dtype detect: bf16 data -> low-half exponent field in [96,160]
__device__ __forceinline__ bool detect_f32(const void* x) {
    const uint32_t* w = (const uint32_t*)x;
    uint32_t v = w[threadIdx.x & 63];
    uint32_t e = (v >> 7) & 0xffu;
    unsigned long long m = __ballot(e >= 96 && e <= 160);
    return __popcll(m) < 40;
}

// workspace layout (float offsets)
#define OFF_U     8         // [256][64]  u = x_pos@k_w1^T + k_b1           (f32)
#define OFF_W     16392     // [256][64]  w = y_pos@k_w1^T                  (f32)
#define OFF_QS    49416     // [256][128] q (scaled)                        (f32)
#define OFF_AX    82184     // [256][128] x @ phi_msg^T                     (f32)
#define OFF_AYP   114952    // [256][128] y @ phi_msg^T - phib              (f32)
#define OFF_GX    147720    // [256][128] x @ g_msg^T                       (f32)
#define OFF_GYP   180488    // [256][128] y @ g_msg^T - gb                  (f32)
#define OFF_PO    213256    // [64 c][4 h][256 q][32]  partial sum(exp*v)   (f32)
#define OFF_PL    2310408   // [64 c][4 h][256 q]      partial sum(exp)     (f32)
#define OFF_WPB   2375944   // [128][64]  bf16 phi_pe @ k_w2
#define OFF_WGB   2380040   // [128][64]  bf16 g_pe @ k_w2
// total < 9.6 MB

// ---------------------------------------------------------------- KA body (templated on dtype)
// roles: [0,128) U/W | [128,192) WPB/WGB | [192,256) k1 GEMM + sbias | [256,260) k2 GEMM
template<bool F32>
__device__ void ka_body(
    const void* __restrict__ x,    const void* __restrict__ y,
    const void* __restrict__ xpos, const void* __restrict__ ypos,
    const void* __restrict__ thw,  const void* __restrict__ phiw,
    const void* __restrict__ gw,
    const void* __restrict__ qw1,  const void* __restrict__ qb1,
    const void* __restrict__ qw2,  const void* __restrict__ qb2,
    const void* __restrict__ kw1,  const void* __restrict__ kb1,
    const void* __restrict__ kw2,  const void* __restrict__ kb2,
    float* __restrict__ ws, char* smem)
{
    const int b = blockIdx.x, t = threadIdx.x;
    const int w = t >> 6, lane = t & 63, quad = lane >> 4, l16 = lane & 15;

    if (b < 128) {                         // ---- R0: U / W (elementwise)
        int id = b*256 + t;
        if (id < 16384) {
            int n = id >> 6, p = id & 63;
            ws[OFF_U + id] = ldT<F32>(kw1,p*3+0)*ldT<F32>(xpos,n*3+0)
                           + ldT<F32>(kw1,p*3+1)*ldT<F32>(xpos,n*3+1)
                           + ldT<F32>(kw1,p*3+2)*ldT<F32>(xpos,n*3+2) + ldT<F32>(kb1,p);
        } else {
            int i = id - 16384; int m = i >> 6, p = i & 63;
            ws[OFF_W + i] = ldT<F32>(kw1,p*3+0)*ldT<F32>(ypos,m*3+0)
                          + ldT<F32>(kw1,p*3+1)*ldT<F32>(ypos,m*3+1)
                          + ldT<F32>(kw1,p*3+2)*ldT<F32>(ypos,m*3+2);
        }
    } else if (b < 192) {                  // ---- R1: WPB / WGB (bf16), straight-line loads
        int id = (b-128)*256 + t;          // 0..16383
        const bool isP = (id < 8192);
        const void* src = isP ? phiw : gw;
        int i = isP ? id : id - 8192;
        int e = i >> 6, p = i & 63;        // e wave-uniform, p = lane -> kw2 coalesced
        float s = 0.f;
        #pragma unroll
        for (int k = 0; k < 16; ++k) {
            short8 a = ldfragT<F32>(src, e*384 + 256 + k*8);
            #pragma unroll
            for (int j = 0; j < 8; ++j)
                s += bs2f(a[j]) * ldT<F32>(kw2, (k*8+j)*64 + p);
        }
        ((short*)(ws + (isP ? OFF_WPB : OFF_WGB)))[i] = f2bs(s);
    } else if (b < 256) {                  // ---- R3: Ax/AyP/Gx/GyP via MFMA (+sbias fold)
        const int bi = b - 192;
        const int which = bi >> 4, rg = bi & 15;
        const void* am = (which & 1) ? y : x;
        const void* wm = (which < 2) ? phiw : gw;
        float* sbias = (float*)smem;
        if (t < 128) {
            float s = 0.f;
            if (which & 1) {               // bias = pe-part @ k_b2 (folded into AyP/GyP)
                const void* pw = (which == 1) ? phiw : gw;
                #pragma unroll
                for (int k = 0; k < 16; ++k) {
                    short8 a  = ldfragT<F32>(pw,  t*384 + 256 + k*8);
                    short8 bb = ldfragT<F32>(kb2, k*8);
                    #pragma unroll
                    for (int j = 0; j < 8; ++j) s += bs2f(a[j]) * bs2f(bb[j]);
                }
            }
            sbias[t] = s;
        }
        __syncthreads();
        const int row0 = rg*16;
        f32x4 acc[2];
        #pragma unroll
        for (int c2 = 0; c2 < 2; ++c2) { acc[c2][0]=0.f; acc[c2][1]=0.f; acc[c2][2]=0.f; acc[c2][3]=0.f; }
        #pragma unroll 2
        for (int k = 0; k < 8; ++k) {
            short8 af = ldfragT<F32>(am, (row0 + l16)*256 + k*32 + quad*8);
            #pragma unroll
            for (int c2 = 0; c2 < 2; ++c2) {
                int ct = w*2 + c2;
                short8 bf = ldfragT<F32>(wm, (ct*16 + l16)*384 + k*32 + quad*8);
                acc[c2] = __builtin_amdgcn_mfma_f32_16x16x32_bf16(af, bf, acc[c2], 0, 0, 0);
            }
        }
        const int base = (which==0) ? OFF_AX : (which==1) ? OFF_AYP : (which==2) ? OFF_GX : OFF_GYP;
        #pragma unroll
        for (int c2 = 0; c2 < 2; ++c2) {
            int col = (w*2+c2)*16 + l16;
            #pragma unroll
            for (int r = 0; r < 4; ++r)
                ws[base + (row0 + quad*4 + r)*128 + col] = acc[c2][r] - sbias[col];
        }
    } else {                               // ---- R4: q = [x|qpe] @ theta^T via MFMA
        const int rg = b - 256;            // 0..3, 64 rows each
        const int row0 = rg*64;
        short* qpe_lds = (short*)smem;              // [64][128] bf16
        short* hq_lds  = (short*)(smem + 16384);    // [64][64]  bf16
        {   // hq = relu(xpos @ q_w1^T + q_b1)
            int row = t >> 2, p0 = (t & 3)*16;
            float px = ldT<F32>(xpos,(row0+row)*3+0);
            float py = ldT<F32>(xpos,(row0+row)*3+1);
            float pz = ldT<F32>(xpos,(row0+row)*3+2);
            #pragma unroll
            for (int i = 0; i < 16; ++i) {
                int p = p0 + i;
                float v = ldT<F32>(qw1,p*3+0)*px + ldT<F32>(qw1,p*3+1)*py
                        + ldT<F32>(qw1,p*3+2)*pz + ldT<F32>(qb1,p);
                hq_lds[row*64 + p] = f2bs(fmaxf(v, 0.f));
            }
        }
        __syncthreads();
        {   // qpe = hq @ q_w2^T + q_b2
            const short8 a0 = *(const short8*)(hq_lds + (w*16 + l16)*64 + quad*8);
            const short8 a1 = *(const short8*)(hq_lds + (w*16 + l16)*64 + 32 + quad*8);
            #pragma unroll
            for (int ct = 0; ct < 8; ++ct) {
                f32x4 acc; acc[0]=0.f; acc[1]=0.f; acc[2]=0.f; acc[3]=0.f;
                short8 b0 = ldfragT<F32>(qw2, (ct*16+l16)*64 + quad*8);
                short8 b1 = ldfragT<F32>(qw2, (ct*16+l16)*64 + 32 + quad*8);
                acc = __builtin_amdgcn_mfma_f32_16x16x32_bf16(a0, b0, acc, 0, 0, 0);
                acc = __builtin_amdgcn_mfma_f32_16x16x32_bf16(a1, b1, acc, 0, 0, 0);
                float qb = ldT<F32>(qb2, ct*16+l16);
                #pragma unroll
                for (int r = 0; r < 4; ++r)
                    qpe_lds[(w*16 + quad*4 + r)*128 + ct*16 + l16] = f2bs(acc[r] + qb);
            }
        }
        __syncthreads();
        f32x4 acc[8];
        #pragma unroll
        for (int ct = 0; ct < 8; ++ct) { acc[ct][0]=0.f; acc[ct][1]=0.f; acc[ct][2]=0.f; acc[ct][3]=0.f; }
        for (int k = 0; k < 12; ++k) {
            const short8 af = (k < 8)
                ? ldfragT<F32>(x, (row0 + w*16 + l16)*256 + k*32 + quad*8)
                : *(const short8*)(qpe_lds + (w*16 + l16)*128 + (k-8)*32 + quad*8);
            #pragma unroll
            for (int ct = 0; ct < 8; ++ct) {
                short8 bf = ldfragT<F32>(thw, (ct*16+l16)*384 + k*32 + quad*8);
                acc[ct] = __builtin_amdgcn_mfma_f32_16x16x32_bf16(af, bf, acc[ct], 0, 0, 0);
            }
        }
        #pragma unroll
        for (int ct = 0; ct < 8; ++ct)
            #pragma unroll
            for (int r = 0; r < 4; ++r)
                ws[OFF_QS + (row0 + w*16 + quad*4 + r)*128 + ct*16 + l16] =
                    acc[ct][r] * 0.17677669529663687f;   // * HD^-0.5
    }
}

__global__ void __launch_bounds__(256) ka_prep(
    const void* __restrict__ x,    const void* __restrict__ y,
    const void* __restrict__ xpos, const void* __restrict__ ypos,
    const void* __restrict__ thw,  const void* __restrict__ phiw,
    const void* __restrict__ gw,
    const void* __restrict__ qw1,  const void* __restrict__ qb1,
    const void* __restrict__ qw2,  const void* __restrict__ qb2,
    const void* __restrict__ kw1,  const void* __restrict__ kb1,
    const void* __restrict__ kw2,  const void* __restrict__ kb2,
    float* __restrict__ ws)
{
    __shared__ alignas(16) char smem[24576 + 512];
    const bool f32 = detect_f32(x);
    if (f32) ka_body<true >(x,y,xpos,ypos,thw,phiw,gw,qw1,qb1,qw2,qb2,kw1,kb1,kw2,kb2,ws,smem);
    else     ka_body<false>(x,y,xpos,ypos,thw,phiw,gw,qw1,qb1,qw2,qb2,kw1,kb1,kw2,kb2,ws,smem);
}

// ---------------------------------------------------------------- K3: MFMA k/v build + attention partials
// grid (c=64, h=4, qh=2), 512 threads (8 waves), 2 blocks/CU. Block: m = c*4..c*4+3,
// queries qh*128..+127. s_p aliases s_hact (phases sync-separated) -> ~75 KB LDS.
__global__ void __launch_bounds__(512, 4) k3_attn(float* __restrict__ ws)
{
    const int c = blockIdx.x, h = blockIdx.y, qh = blockIdx.z;
    const int tid = threadIdx.x;
    const int w = tid >> 6, lane = tid & 63;
    const int quad = lane >> 4, l16 = lane & 15;

    __shared__ float sW[64];
    __shared__ float sAy[32];
    __shared__ float sGy[32];
    __shared__ alignas(16) short s_hact[256*72];   // 36 KB (attn phase: aliased by s_p)
    __shared__ alignas(16) short s_k[256*40];      // 20 KB
    __shared__ alignas(16) short s_vt[32*264];     // 16.5 KB (permuted key order)
    short* const s_p = s_hact;                     // alias: 8 waves x 640 shorts

    const int q0 = qh*128 + w*16;
    short8 qa;
    {
        const float* qp = ws + OFF_QS + (size_t)(q0 + l16)*128 + h*32 + quad*8;
        #pragma unroll
        for (int j = 0; j < 8; ++j) qa[j] = f2bs(qp[j]);
    }

    f32x4 o[2];
    float lp[4];
    #pragma unroll
    for (int d = 0; d < 2; ++d) { o[d][0]=0.f; o[d][1]=0.f; o[d][2]=0.f; o[d][3]=0.f; }
    #pragma unroll
    for (int r = 0; r < 4; ++r) lp[r] = 0.f;

    const int which = w & 1, dtb = (w >> 1) & 1, ktg = w >> 2;
    const short* wbm = (const short*)(ws + (which ? OFF_WGB : OFF_WPB));
    const int ecol = h*32 + dtb*16 + l16;
    const short8 wb0 = *(const short8*)(wbm + ecol*64 + quad*8);
    const short8 wb1 = *(const short8*)(wbm + ecol*64 + 32 + quad*8);
    const float* xb = ws + (which ? OFF_GX : OFF_AX);

    for (int mi = 0; mi < 4; ++mi) {
        const int m = c*4 + mi;
        __syncthreads();   // prior attn (s_p in hact region) done before hact rewrite
        if (tid < 64)       sW[tid]      = ws[OFF_W + m*64 + tid];
        else if (tid < 96)  sAy[tid-64]  = ws[OFF_AYP + m*128 + h*32 + (tid-64)];
        else if (tid < 128) sGy[tid-96]  = ws[OFF_GYP + m*128 + h*32 + (tid-96)];
        __syncthreads();

        {   // hact[key][p] = relu(u[key][p] - w[m][p])
            const int key = tid >> 1, half = tid & 1;
            const float4* up = (const float4*)(ws + OFF_U + key*64 + half*32);
            short* hd = s_hact + key*72 + half*32;
            #pragma unroll
            for (int i = 0; i < 8; ++i) {
                float4 u4 = up[i]; int p = half*32 + i*4;
                hd[i*4+0] = f2bs(fmaxf(u4.x - sW[p+0], 0.f));
                hd[i*4+1] = f2bs(fmaxf(u4.y - sW[p+1], 0.f));
                hd[i*4+2] = f2bs(fmaxf(u4.z - sW[p+2], 0.f));
                hd[i*4+3] = f2bs(fmaxf(u4.w - sW[p+3], 0.f));
            }
        }
        __syncthreads();

        {   // K/V build via MFMA
            const float ycol = (which ? sGy : sAy)[dtb*16 + l16];
            #pragma unroll 2
            for (int i = 0; i < 8; ++i) {
                const int kt = ktg*8 + i;
                f32x4 acc;
                #pragma unroll
                for (int r = 0; r < 4; ++r)
                    acc[r] = xb[(size_t)(kt*16 + quad*4 + r)*128 + ecol] - ycol;
                const short8 a0 = *(const short8*)(s_hact + (kt*16 + l16)*72 + quad*8);
                const short8 a1 = *(const short8*)(s_hact + (kt*16 + l16)*72 + 32 + quad*8);
                acc = __builtin_amdgcn_mfma_f32_16x16x32_bf16(a0, wb0, acc, 0, 0, 0);
                acc = __builtin_amdgcn_mfma_f32_16x16x32_bf16(a1, wb1, acc, 0, 0, 0);
                if (which == 0) {
                    #pragma unroll
                    for (int r = 0; r < 4; ++r)
                        s_k[(kt*16 + quad*4 + r)*40 + dtb*16 + l16] = f2bs(acc[r]);
                } else {
                    const int kp = (kt >> 1)*32 + ((quad*4)<<1) + (kt & 1);  // permuted col
                    #pragma unroll
                    for (int r = 0; r < 4; ++r)
                        s_vt[(dtb*16 + l16)*264 + kp + (r<<1)] = f2bs(acc[r]);
                }
            }
        }
        __syncthreads();

        // attention: per 32-key chunk: scores -> exp -> P(LDS, packed) -> PV
        for (int kc = 0; kc < 8; ++kc) {
            const short8 kb0 = *(const short8*)(s_k + (kc*32 + l16)*40 + quad*8);
            const short8 kb1 = *(const short8*)(s_k + (kc*32 + 16 + l16)*40 + quad*8);
            const short8 vb0 = *(const short8*)(s_vt + l16*264 + kc*32 + quad*8);
            const short8 vb1 = *(const short8*)(s_vt + (16 + l16)*264 + kc*32 + quad*8);
            f32x4 z; z[0]=0.f; z[1]=0.f; z[2]=0.f; z[3]=0.f;
            f32x4 s0 = __builtin_amdgcn_mfma_f32_16x16x32_bf16(qa, kb0, z, 0, 0, 0);
            f32x4 s1 = __builtin_amdgcn_mfma_f32_16x16x32_bf16(qa, kb1, z, 0, 0, 0);
            short* pb = s_p + w*640;
            #pragma unroll
            for (int r = 0; r < 4; ++r) {
                float e0 = __expf(s0[r]);
                float e1 = __expf(s1[r]);
                lp[r] += e0 + e1;
                uint32_t pk = (uint32_t)(uint16_t)f2bs(e0)
                            | ((uint32_t)(uint16_t)f2bs(e1) << 16);
                *(uint32_t*)(pb + (quad*4+r)*40 + 2*l16) = pk;
            }
            const short8 pa = *(const short8*)(pb + l16*40 + quad*8);
            o[0] = __builtin_amdgcn_mfma_f32_16x16x32_bf16(pa, vb0, o[0], 0, 0, 0);
            o[1] = __builtin_amdgcn_mfma_f32_16x16x32_bf16(pa, vb1, o[1], 0, 0, 0);
        }
    }

    #pragma unroll
    for (int dtl = 0; dtl < 2; ++dtl)
        #pragma unroll
        for (int r = 0; r < 4; ++r)
            ws[OFF_PO + (size_t)((c*4 + h)*256 + q0 + quad*4 + r)*32 + dtl*16 + l16] = o[dtl][r];
    #pragma unroll
    for (int r = 0; r < 4; ++r) {
        float v = lp[r];
        v += __shfl_xor(v, 1); v += __shfl_xor(v, 2);
        v += __shfl_xor(v, 4); v += __shfl_xor(v, 8);
        if (l16 == 0)
            ws[OFF_PL + (c*4 + h)*256 + q0 + quad*4 + r] = v;
    }
}

// ---------------------------------------------------------------- K4 body (templated on dtype)
template<bool F32>
__device__ void k4_body(
    const float* __restrict__ ws, const void* __restrict__ x,
    const void* __restrict__ outw, const void* __restrict__ lng,
    const void* __restrict__ lnb, void* __restrict__ outp,
    float (*pl4)[256], float* red, float* o2, float* stat)
{
    int q = blockIdx.x, t = threadIdx.x;

    #pragma unroll
    for (int h = 0; h < 4; ++h)
        pl4[h][t] = (t < 64) ? ws[OFF_PL + (t*4 + h)*256 + q] : 0.f;
    __syncthreads();
    for (int s = 128; s > 0; s >>= 1) {
        if (t < s) {
            pl4[0][t] += pl4[0][t+s]; pl4[1][t] += pl4[1][t+s];
            pl4[2][t] += pl4[2][t+s]; pl4[3][t] += pl4[3][t+s];
        }
        __syncthreads();
    }
    int e = t & 127, h2 = e >> 5, d = e & 31, half = t >> 7;
    float a = 0.f;
    #pragma unroll
    for (int mm = 0; mm < 32; ++mm) {
        int c = half*32 + mm;
        a += ws[OFF_PO + ((c*4 + h2)*256 + q)*32 + d];
    }
    red[t] = a;
    __syncthreads();
    if (t < 128) o2[t] = (red[t] + red[t+128]) / pl4[t>>5][0];
    __syncthreads();

    float rv = ldT<F32>(x, q*256 + t);
    #pragma unroll
    for (int i = 0; i < 16; ++i) {
        short8 wv = ldfragT<F32>(outw, t*128 + i*8);
        #pragma unroll
        for (int j = 0; j < 8; ++j) rv += o2[i*8+j]*bs2f(wv[j]);
    }
    red[t] = rv; __syncthreads();
    for (int s = 128; s > 0; s >>= 1) { if (t < s) red[t] += red[t+s]; __syncthreads(); }
    if (t == 0) stat[0] = red[0] * (1.f/256.f);
    __syncthreads();
    float mu = stat[0];
    float dv = rv - mu;
    red[t] = dv*dv; __syncthreads();
    for (int s = 128; s > 0; s >>= 1) { if (t < s) red[t] += red[t+s]; __syncthreads(); }
    if (t == 0) stat[1] = red[0] * (1.f/256.f);
    __syncthreads();
    float rstd = rsqrtf(stat[1] + 1e-5f);
    float val = dv*rstd*ldT<F32>(lng,t) + ldT<F32>(lnb,t);
    if constexpr (F32) ((float*)outp)[q*256 + t] = val;
    else               ((bf16*)outp)[q*256 + t] = __float2bfloat16(val);
}

__global__ void __launch_bounds__(256) k4_out(
    const float* __restrict__ ws, const void* __restrict__ x,
    const void* __restrict__ outw, const void* __restrict__ lng,
    const void* __restrict__ lnb, void* __restrict__ outp)
{
    __shared__ float pl4[4][256];
    __shared__ float red[256];
    __shared__ float o2[128];
    __shared__ float stat[2];
    const bool f32 = detect_f32(x);
    if (f32) k4_body<true >(ws, x, outw, lng, lnb, outp, pl4, red, o2, stat);
    else     k4_body<false>(ws, x, outw, lng, lnb, outp, pl4, red, o2, stat);
}

// ----------------------------------------------------------------
extern "C" void kernel_launch(void* const* d_in, const int* in_sizes, int n_in,
                              void* d_out, int out_size, void* d_ws, size_t ws_size,
                              hipStream_t stream)
{
    const void* x    = d_in[0];
    const void* y    = d_in[1];
    const void* xpos = d_in[2];
    const void* ypos = d_in[3];
    const void* thw  = d_in[4];
    const void* phiw = d_in[5];
    const void* gw   = d_in[6];
    const void* qw1  = d_in[7];
    const void* qb1  = d_in[8];
    const void* qw2  = d_in[9];
    const void* qb2  = d_in[10];
    const void* kw1  = d_in[11];
    const void* kb1  = d_in[12];
    const void* kw2  = d_in[13];
    const void* kb2  = d_in[14];
    const void* outw = d_in[15];
    const void* lng  = d_in[16];
    const void* lnb  = d_in[17];
    float* ws = (float*)d_ws;

    ka_prep<<<260, 256, 0, stream>>>(x, y, xpos, ypos, thw, phiw, gw,
                                     qw1, qb1, qw2, qb2, kw1, kb1, kw2, kb2, ws);
    k3_attn<<<dim3(64, 4, 2), 512, 0, stream>>>(ws);
    k4_out<<<256, 256, 0, stream>>>(ws, x, outw, lng, lnb, d_out);
}

// Round 9
// 169.428 us; speedup vs baseline: 3.3819x; 1.1162x over previous
//
#include <hip/hip_runtime.h>
#include <hip/hip_bf16.h>
#include <stdint.h>

// Problem: B=1, N=M=256, D=256, E=128, H=4, HD=32, P=64
typedef __hip_bfloat16 bf16;
typedef __attribute__((ext_vector_type(8))) short short8;
typedef __attribute__((ext_vector_type(4))) float f32x4;

__device__ __forceinline__ float b2f(bf16 v) { return __bfloat162float(v); }
__device__ __forceinline__ short f2bs(float f) {
    __hip_bfloat16 h = __float2bfloat16(f);
    return *reinterpret_cast<short*>(&h);
}
__device__ __forceinline__ float bs2f(short s) {
    union { uint32_t u; float f; } c; c.u = ((uint32_t)(uint16_t)s) << 16; return c.f;
}
// compile-time dtype loads (branch hoisted to kernel top)
template<bool F32> __device__ __forceinline__ float ldT(const void* p, int i) {
    if constexpr (F32) return ((const float*)p)[i];
    else               return b2f(((const bf16*)p)[i]);
}
template<bool F32> __device__ __forceinline__ short8 ldfragT(const void* p, int idx) {
    if constexpr (F32) {
        const float4* q = (const float4*)((const float*)p + idx);
        float4 a = q[0], b = q[1];
        short8 r;
        r[0]=f2bs(a.x); r[1]=f2bs(a.y); r[2]=f2bs(a.z); r[3]=f2bs(a.w);
        r[4]=f2bs(b.x); r[5]=f2bs(b.y); r[6]=f2bs(b.z); r[7]=f2bs(b.w);
        return r;
    } else {
        return *(const short8*)((const short*)p + idx);
    }
}
// per-block dtype detect: bf16 data -> low-half exponent field in [96,160]
__device__ __forceinline__ bool detect_f32(const void* x) {
    const uint32_t* w = (const uint32_t*)x;
    uint32_t v = w[threadIdx.x & 63];
    uint32_t e = (v >> 7) & 0xffu;
    unsigned long long m = __ballot(e >= 96 && e <= 160);
    return __popcll(m) < 40;
}

// workspace layout (float offsets)
#define OFF_U     8         // [256][64]  u = x_pos@k_w1^T + k_b1           (f32)
#define OFF_W     16392     // [256][64]  w = y_pos@k_w1^T                  (f32)
#define OFF_QS    49416     // [256][128] q (scaled)                        (f32)
#define OFF_AX    82184     // [256][128] x @ phi_msg^T                     (f32)
#define OFF_AYP   114952    // [256][128] y @ phi_msg^T - phib              (f32)
#define OFF_GX    147720    // [256][128] x @ g_msg^T                       (f32)
#define OFF_GYP   180488    // [256][128] y @ g_msg^T - gb                  (f32)
#define OFF_PO    213256    // [64 c][4 h][256 q][32]  partial sum(exp*v)   (f32)
#define OFF_PL    2310408   // [64 c][4 h][256 q]      partial sum(exp)     (f32)
#define OFF_WPB   2375944   // [128][64]  bf16 phi_pe @ k_w2
#define OFF_WGB   2380040   // [128][64]  bf16 g_pe @ k_w2
// total < 9.6 MB

// ---------------------------------------------------------------- KA1: U / W (elementwise), 128 blocks
template<bool F32>
__device__ void ka1_body(const void* xpos, const void* ypos,
                         const void* kw1, const void* kb1, float* ws)
{
    int id = blockIdx.x*256 + threadIdx.x;
    if (id < 16384) {
        int n = id >> 6, p = id & 63;
        ws[OFF_U + id] = ldT<F32>(kw1,p*3+0)*ldT<F32>(xpos,n*3+0)
                       + ldT<F32>(kw1,p*3+1)*ldT<F32>(xpos,n*3+1)
                       + ldT<F32>(kw1,p*3+2)*ldT<F32>(xpos,n*3+2) + ldT<F32>(kb1,p);
    } else {
        int i = id - 16384; int m = i >> 6, p = i & 63;
        ws[OFF_W + i] = ldT<F32>(kw1,p*3+0)*ldT<F32>(ypos,m*3+0)
                      + ldT<F32>(kw1,p*3+1)*ldT<F32>(ypos,m*3+1)
                      + ldT<F32>(kw1,p*3+2)*ldT<F32>(ypos,m*3+2);
    }
}
__global__ void __launch_bounds__(256) ka1_elem(
    const void* __restrict__ x, const void* __restrict__ xpos, const void* __restrict__ ypos,
    const void* __restrict__ kw1, const void* __restrict__ kb1, float* __restrict__ ws)
{
    if (detect_f32(x)) ka1_body<true >(xpos, ypos, kw1, kb1, ws);
    else               ka1_body<false>(xpos, ypos, kw1, kb1, ws);
}

// ---------------------------------------------------------------- KA2: WPB / WGB, 64 blocks
template<bool F32>
__device__ void ka2_body(const void* phiw, const void* gw, const void* kw2, float* ws)
{
    int id = blockIdx.x*256 + threadIdx.x;   // 0..16383
    const bool isP = (id < 8192);
    const void* src = isP ? phiw : gw;
    int i = isP ? id : id - 8192;
    int e = i >> 6, p = i & 63;              // e wave-uniform, p = lane -> kw2 coalesced
    float s = 0.f;
    #pragma unroll
    for (int k = 0; k < 16; ++k) {
        short8 a = ldfragT<F32>(src, e*384 + 256 + k*8);
        #pragma unroll
        for (int j = 0; j < 8; ++j)
            s += bs2f(a[j]) * ldT<F32>(kw2, (k*8+j)*64 + p);
    }
    ((short*)(ws + (isP ? OFF_WPB : OFF_WGB)))[i] = f2bs(s);
}
__global__ void __launch_bounds__(256) ka2_wpb(
    const void* __restrict__ x, const void* __restrict__ phiw,
    const void* __restrict__ gw, const void* __restrict__ kw2, float* __restrict__ ws)
{
    if (detect_f32(x)) ka2_body<true >(phiw, gw, kw2, ws);
    else               ka2_body<false>(phiw, gw, kw2, ws);
}

// ---------------------------------------------------------------- KA3: Ax/AyP/Gx/GyP via MFMA, 64 blocks
template<bool F32>
__device__ void ka3_body(const void* x, const void* y, const void* phiw,
                         const void* gw, const void* kb2, float* ws, float* sbias)
{
    const int bi = blockIdx.x, t = threadIdx.x;
    const int w = t >> 6, lane = t & 63, quad = lane >> 4, l16 = lane & 15;
    const int which = bi >> 4, rg = bi & 15;
    const void* am = (which & 1) ? y : x;
    const void* wm = (which < 2) ? phiw : gw;
    if (t < 128) {
        float s = 0.f;
        if (which & 1) {               // bias = pe-part @ k_b2 (folded into AyP/GyP)
            const void* pw = (which == 1) ? phiw : gw;
            #pragma unroll
            for (int k = 0; k < 16; ++k) {
                short8 a  = ldfragT<F32>(pw,  t*384 + 256 + k*8);
                short8 bb = ldfragT<F32>(kb2, k*8);
                #pragma unroll
                for (int j = 0; j < 8; ++j) s += bs2f(a[j]) * bs2f(bb[j]);
            }
        }
        sbias[t] = s;
    }
    __syncthreads();
    const int row0 = rg*16;
    f32x4 acc[2];
    #pragma unroll
    for (int c2 = 0; c2 < 2; ++c2) { acc[c2][0]=0.f; acc[c2][1]=0.f; acc[c2][2]=0.f; acc[c2][3]=0.f; }
    #pragma unroll 2
    for (int k = 0; k < 8; ++k) {
        short8 af = ldfragT<F32>(am, (row0 + l16)*256 + k*32 + quad*8);
        #pragma unroll
        for (int c2 = 0; c2 < 2; ++c2) {
            int ct = w*2 + c2;
            short8 bf = ldfragT<F32>(wm, (ct*16 + l16)*384 + k*32 + quad*8);
            acc[c2] = __builtin_amdgcn_mfma_f32_16x16x32_bf16(af, bf, acc[c2], 0, 0, 0);
        }
    }
    const int base = (which==0) ? OFF_AX : (which==1) ? OFF_AYP : (which==2) ? OFF_GX : OFF_GYP;
    #pragma unroll
    for (int c2 = 0; c2 < 2; ++c2) {
        int col = (w*2+c2)*16 + l16;
        #pragma unroll
        for (int r = 0; r < 4; ++r)
            ws[base + (row0 + quad*4 + r)*128 + col] = acc[c2][r] - sbias[col];
    }
}
__global__ void __launch_bounds__(256) ka3_kproj(
    const void* __restrict__ x, const void* __restrict__ y, const void* __restrict__ phiw,
    const void* __restrict__ gw, const void* __restrict__ kb2, float* __restrict__ ws)
{
    __shared__ float sbias[128];
    if (detect_f32(x)) ka3_body<true >(x, y, phiw, gw, kb2, ws, sbias);
    else               ka3_body<false>(x, y, phiw, gw, kb2, ws, sbias);
}

// ---------------------------------------------------------------- KA4: q = [x|qpe] @ theta^T via MFMA, 16 blocks
template<bool F32>
__device__ void ka4_body(const void* x, const void* xpos, const void* thw,
                         const void* qw1, const void* qb1,
                         const void* qw2, const void* qb2,
                         float* ws, char* smem)
{
    const int t = threadIdx.x;
    const int w = t >> 6, lane = t & 63, quad = lane >> 4, l16 = lane & 15;
    const int row0 = blockIdx.x*16;             // 16 rows per block
    short* qpe_lds = (short*)smem;              // [16][128] bf16 (4 KB)
    short* hq_lds  = (short*)(smem + 4096);     // [16][64]  bf16 (2 KB)
    {   // hq = relu(xpos @ q_w1^T + q_b1)
        int row = t >> 4, p0 = (t & 15)*4;
        float px = ldT<F32>(xpos,(row0+row)*3+0);
        float py = ldT<F32>(xpos,(row0+row)*3+1);
        float pz = ldT<F32>(xpos,(row0+row)*3+2);
        #pragma unroll
        for (int i = 0; i < 4; ++i) {
            int p = p0 + i;
            float v = ldT<F32>(qw1,p*3+0)*px + ldT<F32>(qw1,p*3+1)*py
                    + ldT<F32>(qw1,p*3+2)*pz + ldT<F32>(qb1,p);
            hq_lds[row*64 + p] = f2bs(fmaxf(v, 0.f));
        }
    }
    __syncthreads();
    {   // qpe = hq @ q_w2^T + q_b2 (8 col-tiles over 4 waves)
        const short8 a0 = *(const short8*)(hq_lds + l16*64 + quad*8);
        const short8 a1 = *(const short8*)(hq_lds + l16*64 + 32 + quad*8);
        #pragma unroll
        for (int c2 = 0; c2 < 2; ++c2) {
            int ct = w*2 + c2;
            f32x4 acc; acc[0]=0.f; acc[1]=0.f; acc[2]=0.f; acc[3]=0.f;
            short8 b0 = ldfragT<F32>(qw2, (ct*16+l16)*64 + quad*8);
            short8 b1 = ldfragT<F32>(qw2, (ct*16+l16)*64 + 32 + quad*8);
            acc = __builtin_amdgcn_mfma_f32_16x16x32_bf16(a0, b0, acc, 0, 0, 0);
            acc = __builtin_amdgcn_mfma_f32_16x16x32_bf16(a1, b1, acc, 0, 0, 0);
            float qb = ldT<F32>(qb2, ct*16+l16);
            #pragma unroll
            for (int r = 0; r < 4; ++r)
                qpe_lds[(quad*4 + r)*128 + ct*16 + l16] = f2bs(acc[r] + qb);
        }
    }
    __syncthreads();
    f32x4 acc[2];
    #pragma unroll
    for (int c2 = 0; c2 < 2; ++c2) { acc[c2][0]=0.f; acc[c2][1]=0.f; acc[c2][2]=0.f; acc[c2][3]=0.f; }
    for (int k = 0; k < 12; ++k) {
        const short8 af = (k < 8)
            ? ldfragT<F32>(x, (row0 + l16)*256 + k*32 + quad*8)
            : *(const short8*)(qpe_lds + l16*128 + (k-8)*32 + quad*8);
        #pragma unroll
        for (int c2 = 0; c2 < 2; ++c2) {
            int ct = w*2 + c2;
            short8 bf = ldfragT<F32>(thw, (ct*16+l16)*384 + k*32 + quad*8);
            acc[c2] = __builtin_amdgcn_mfma_f32_16x16x32_bf16(af, bf, acc[c2], 0, 0, 0);
        }
    }
    #pragma unroll
    for (int c2 = 0; c2 < 2; ++c2)
        #pragma unroll
        for (int r = 0; r < 4; ++r)
            ws[OFF_QS + (row0 + quad*4 + r)*128 + (w*2+c2)*16 + l16] =
                acc[c2][r] * 0.17677669529663687f;   // * HD^-0.5
}
__global__ void __launch_bounds__(256) ka4_q(
    const void* __restrict__ x, const void* __restrict__ xpos, const void* __restrict__ thw,
    const void* __restrict__ qw1, const void* __restrict__ qb1,
    const void* __restrict__ qw2, const void* __restrict__ qb2, float* __restrict__ ws)
{
    __shared__ alignas(16) char smem[6144];
    if (detect_f32(x)) ka4_body<true >(x, xpos, thw, qw1, qb1, qw2, qb2, ws, smem);
    else               ka4_body<false>(x, xpos, thw, qw1, qb1, qw2, qb2, ws, smem);
}

// ---------------------------------------------------------------- K3: MFMA k/v build + attention partials
// grid (c=64, h=4, qh=2), 512 threads (8 waves), 2 blocks/CU. Block: m = c*4..c*4+3,
// queries qh*128..+127. s_p aliases s_hact (phases sync-separated) -> ~75 KB LDS.
__global__ void __launch_bounds__(512, 4) k3_attn(float* __restrict__ ws)
{
    const int c = blockIdx.x, h = blockIdx.y, qh = blockIdx.z;
    const int tid = threadIdx.x;
    const int w = tid >> 6, lane = tid & 63;
    const int quad = lane >> 4, l16 = lane & 15;

    __shared__ float sW[64];
    __shared__ float sAy[32];
    __shared__ float sGy[32];
    __shared__ alignas(16) short s_hact[256*72];   // 36 KB (attn phase: aliased by s_p)
    __shared__ alignas(16) short s_k[256*40];      // 20 KB
    __shared__ alignas(16) short s_vt[32*264];     // 16.5 KB (permuted key order)
    short* const s_p = s_hact;                     // alias: 8 waves x 640 shorts

    const int q0 = qh*128 + w*16;
    short8 qa;
    {
        const float* qp = ws + OFF_QS + (size_t)(q0 + l16)*128 + h*32 + quad*8;
        #pragma unroll
        for (int j = 0; j < 8; ++j) qa[j] = f2bs(qp[j]);
    }

    f32x4 o[2];
    float lp[4];
    #pragma unroll
    for (int d = 0; d < 2; ++d) { o[d][0]=0.f; o[d][1]=0.f; o[d][2]=0.f; o[d][3]=0.f; }
    #pragma unroll
    for (int r = 0; r < 4; ++r) lp[r] = 0.f;

    const int which = w & 1, dtb = (w >> 1) & 1, ktg = w >> 2;
    const short* wbm = (const short*)(ws + (which ? OFF_WGB : OFF_WPB));
    const int ecol = h*32 + dtb*16 + l16;
    const short8 wb0 = *(const short8*)(wbm + ecol*64 + quad*8);
    const short8 wb1 = *(const short8*)(wbm + ecol*64 + 32 + quad*8);
    const float* xb = ws + (which ? OFF_GX : OFF_AX);

    for (int mi = 0; mi < 4; ++mi) {
        const int m = c*4 + mi;
        __syncthreads();   // prior attn (s_p in hact region) done before hact rewrite
        if (tid < 64)       sW[tid]      = ws[OFF_W + m*64 + tid];
        else if (tid < 96)  sAy[tid-64]  = ws[OFF_AYP + m*128 + h*32 + (tid-64)];
        else if (tid < 128) sGy[tid-96]  = ws[OFF_GYP + m*128 + h*32 + (tid-96)];
        __syncthreads();

        {   // hact[key][p] = relu(u[key][p] - w[m][p])
            const int key = tid >> 1, half = tid & 1;
            const float4* up = (const float4*)(ws + OFF_U + key*64 + half*32);
            short* hd = s_hact + key*72 + half*32;
            #pragma unroll
            for (int i = 0; i < 8; ++i) {
                float4 u4 = up[i]; int p = half*32 + i*4;
                hd[i*4+0] = f2bs(fmaxf(u4.x - sW[p+0], 0.f));
                hd[i*4+1] = f2bs(fmaxf(u4.y - sW[p+1], 0.f));
                hd[i*4+2] = f2bs(fmaxf(u4.z - sW[p+2], 0.f));
                hd[i*4+3] = f2bs(fmaxf(u4.w - sW[p+3], 0.f));
            }
        }
        __syncthreads();

        {   // K/V build via MFMA
            const float ycol = (which ? sGy : sAy)[dtb*16 + l16];
            #pragma unroll 2
            for (int i = 0; i < 8; ++i) {
                const int kt = ktg*8 + i;
                f32x4 acc;
                #pragma unroll
                for (int r = 0; r < 4; ++r)
                    acc[r] = xb[(size_t)(kt*16 + quad*4 + r)*128 + ecol] - ycol;
                const short8 a0 = *(const short8*)(s_hact + (kt*16 + l16)*72 + quad*8);
                const short8 a1 = *(const short8*)(s_hact + (kt*16 + l16)*72 + 32 + quad*8);
                acc = __builtin_amdgcn_mfma_f32_16x16x32_bf16(a0, wb0, acc, 0, 0, 0);
                acc = __builtin_amdgcn_mfma_f32_16x16x32_bf16(a1, wb1, acc, 0, 0, 0);
                if (which == 0) {
                    #pragma unroll
                    for (int r = 0; r < 4; ++r)
                        s_k[(kt*16 + quad*4 + r)*40 + dtb*16 + l16] = f2bs(acc[r]);
                } else {
                    const int kp = (kt >> 1)*32 + ((quad*4)<<1) + (kt & 1);  // permuted col
                    #pragma unroll
                    for (int r = 0; r < 4; ++r)
                        s_vt[(dtb*16 + l16)*264 + kp + (r<<1)] = f2bs(acc[r]);
                }
            }
        }
        __syncthreads();

        // attention: per 32-key chunk: scores -> exp -> P(LDS, packed) -> PV
        for (int kc = 0; kc < 8; ++kc) {
            const short8 kb0 = *(const short8*)(s_k + (kc*32 + l16)*40 + quad*8);
            const short8 kb1 = *(const short8*)(s_k + (kc*32 + 16 + l16)*40 + quad*8);
            const short8 vb0 = *(const short8*)(s_vt + l16*264 + kc*32 + quad*8);
            const short8 vb1 = *(const short8*)(s_vt + (16 + l16)*264 + kc*32 + quad*8);
            f32x4 z; z[0]=0.f; z[1]=0.f; z[2]=0.f; z[3]=0.f;
            f32x4 s0 = __builtin_amdgcn_mfma_f32_16x16x32_bf16(qa, kb0, z, 0, 0, 0);
            f32x4 s1 = __builtin_amdgcn_mfma_f32_16x16x32_bf16(qa, kb1, z, 0, 0, 0);
            short* pb = s_p + w*640;
            #pragma unroll
            for (int r = 0; r < 4; ++r) {
                float e0 = __expf(s0[r]);
                float e1 = __expf(s1[r]);
                lp[r] += e0 + e1;
                uint32_t pk = (uint32_t)(uint16_t)f2bs(e0)
                            | ((uint32_t)(uint16_t)f2bs(e1) << 16);
                *(uint32_t*)(pb + (quad*4+r)*40 + 2*l16) = pk;
            }
            const short8 pa = *(const short8*)(pb + l16*40 + quad*8);
            o[0] = __builtin_amdgcn_mfma_f32_16x16x32_bf16(pa, vb0, o[0], 0, 0, 0);
            o[1] = __builtin_amdgcn_mfma_f32_16x16x32_bf16(pa, vb1, o[1], 0, 0, 0);
        }
    }

    #pragma unroll
    for (int dtl = 0; dtl < 2; ++dtl)
        #pragma unroll
        for (int r = 0; r < 4; ++r)
            ws[OFF_PO + (size_t)((c*4 + h)*256 + q0 + quad*4 + r)*32 + dtl*16 + l16] = o[dtl][r];
    #pragma unroll
    for (int r = 0; r < 4; ++r) {
        float v = lp[r];
        v += __shfl_xor(v, 1); v += __shfl_xor(v, 2);
        v += __shfl_xor(v, 4); v += __shfl_xor(v, 8);
        if (l16 == 0)
            ws[OFF_PL + (c*4 + h)*256 + q0 + quad*4 + r] = v;
    }
}

// ---------------------------------------------------------------- K4 body (templated on dtype)
template<bool F32>
__device__ void k4_body(
    const float* __restrict__ ws, const void* __restrict__ x,
    const void* __restrict__ outw, const void* __restrict__ lng,
    const void* __restrict__ lnb, void* __restrict__ outp,
    float (*pl4)[256], float* red, float* o2, float* stat)
{
    int q = blockIdx.x, t = threadIdx.x;

    #pragma unroll
    for (int h = 0; h < 4; ++h)
        pl4[h][t] = (t < 64) ? ws[OFF_PL + (t*4 + h)*256 + q] : 0.f;
    __syncthreads();
    for (int s = 128; s > 0; s >>= 1) {
        if (t < s) {
            pl4[0][t] += pl4[0][t+s]; pl4[1][t] += pl4[1][t+s];
            pl4[2][t] += pl4[2][t+s]; pl4[3][t] += pl4[3][t+s];
        }
        __syncthreads();
    }
    int e = t & 127, h2 = e >> 5, d = e & 31, half = t >> 7;
    float a = 0.f;
    #pragma unroll
    for (int mm = 0; mm < 32; ++mm) {
        int c = half*32 + mm;
        a += ws[OFF_PO + ((c*4 + h2)*256 + q)*32 + d];
    }
    red[t] = a;
    __syncthreads();
    if (t < 128) o2[t] = (red[t] + red[t+128]) / pl4[t>>5][0];
    __syncthreads();

    float rv = ldT<F32>(x, q*256 + t);
    #pragma unroll
    for (int i = 0; i < 16; ++i) {
        short8 wv = ldfragT<F32>(outw, t*128 + i*8);
        #pragma unroll
        for (int j = 0; j < 8; ++j) rv += o2[i*8+j]*bs2f(wv[j]);
    }
    red[t] = rv; __syncthreads();
    for (int s = 128; s > 0; s >>= 1) { if (t < s) red[t] += red[t+s]; __syncthreads(); }
    if (t == 0) stat[0] = red[0] * (1.f/256.f);
    __syncthreads();
    float mu = stat[0];
    float dv = rv - mu;
    red[t] = dv*dv; __syncthreads();
    for (int s = 128; s > 0; s >>= 1) { if (t < s) red[t] += red[t+s]; __syncthreads(); }
    if (t == 0) stat[1] = red[0] * (1.f/256.f);
    __syncthreads();
    float rstd = rsqrtf(stat[1] + 1e-5f);
    float val = dv*rstd*ldT<F32>(lng,t) + ldT<F32>(lnb,t);
    if constexpr (F32) ((float*)outp)[q*256 + t] = val;
    else               ((bf16*)outp)[q*256 + t] = __float2bfloat16(val);
}

__global__ void __launch_bounds__(256) k4_out(
    const float* __restrict__ ws, const void* __restrict__ x,
    const void* __restrict__ outw, const void* __restrict__ lng,
    const void* __restrict__ lnb, void* __restrict__ outp)
{
    __shared__ float pl4[4][256];
    __shared__ float red[256];
    __shared__ float o2[128];
    __shared__ float stat[2];
    const bool f32 = detect_f32(x);
    if (f32) k4_body<true >(ws, x, outw, lng, lnb, outp, pl4, red, o2, stat);
    else     k4_body<false>(ws, x, outw, lng, lnb, outp, pl4, red, o2, stat);
}

// ----------------------------------------------------------------
extern "C" void kernel_launch(void* const* d_in, const int* in_sizes, int n_in,
                              void* d_out, int out_size, void* d_ws, size_t ws_size,
                              hipStream_t stream)
{
    const void* x    = d_in[0];
    const void* y    = d_in[1];
    const void* xpos = d_in[2];
    const void* ypos = d_in[3];
    const void* thw  = d_in[4];
    const void* phiw = d_in[5];
    const void* gw   = d_in[6];
    const void* qw1  = d_in[7];
    const void* qb1  = d_in[8];
    const void* qw2  = d_in[9];
    const void* qb2  = d_in[10];
    const void* kw1  = d_in[11];
    const void* kb1  = d_in[12];
    const void* kw2  = d_in[13];
    const void* kb2  = d_in[14];
    const void* outw = d_in[15];
    const void* lng  = d_in[16];
    const void* lnb  = d_in[17];
    float* ws = (float*)d_ws;

    ka1_elem<<<128, 256, 0, stream>>>(x, xpos, ypos, kw1, kb1, ws);
    ka2_wpb<<<64, 256, 0, stream>>>(x, phiw, gw, kw2, ws);
    ka3_kproj<<<64, 256, 0, stream>>>(x, y, phiw, gw, kb2, ws);
    ka4_q<<<16, 256, 0, stream>>>(x, xpos, thw, qw1, qb1, qw2, qb2, ws);
    k3_attn<<<dim3(64, 4, 2), 512, 0, stream>>>(ws);
    k4_out<<<256, 256, 0, stream>>>(ws, x, outw, lng, lnb, d_out);
}

// Round 10
// 167.045 us; speedup vs baseline: 3.4302x; 1.0143x over previous
//
#include <hip/hip_runtime.h>
#include <hip/hip_bf16.h>
#include <stdint.h>

// Problem: B=1, N=M=256, D=256, E=128, H=4, HD=32, P=64
typedef __hip_bfloat16 bf16;
typedef __attribute__((ext_vector_type(8))) short short8;
typedef __attribute__((ext_vector_type(4))) float f32x4;

__device__ __forceinline__ float b2f(bf16 v) { return __bfloat162float(v); }
__device__ __forceinline__ short f2bs(float f) {
    __hip_bfloat16 h = __float2bfloat16(f);
    return *reinterpret_cast<short*>(&h);
}
__device__ __forceinline__ float bs2f(short s) {
    union { uint32_t u; float f; } c; c.u = ((uint32_t)(uint16_t)s) << 16; return c.f;
}
// compile-time dtype loads (branch hoisted to kernel top)
template<bool F32> __device__ __forceinline__ float ldT(const void* p, int i) {
    if constexpr (F32) return ((const float*)p)[i];
    else               return b2f(((const bf16*)p)[i]);
}
template<bool F32> __device__ __forceinline__ short8 ldfragT(const void* p, int idx) {
    if constexpr (F32) {
        const float4* q = (const float4*)((const float*)p + idx);
        float4 a = q[0], b = q[1];
        short8 r;
        r[0]=f2bs(a.x); r[1]=f2bs(a.y); r[2]=f2bs(a.z); r[3]=f2bs(a.w);
        r[4]=f2bs(b.x); r[5]=f2bs(b.y); r[6]=f2bs(b.z); r[7]=f2bs(b.w);
        return r;
    } else {
        return *(const short8*)((const short*)p + idx);
    }
}
// per-block dtype detect: bf16 data -> low-half exponent field in [96,160]
__device__ __forceinline__ bool detect_f32(const void* x) {
    const uint32_t* w = (const uint32_t*)x;
    uint32_t v = w[threadIdx.x & 63];
    uint32_t e = (v >> 7) & 0xffu;
    unsigned long long m = __ballot(e >= 96 && e <= 160);
    return __popcll(m) < 40;
}

// workspace layout (float offsets)
#define OFF_U     8         // [256][64]  u = x_pos@k_w1^T + k_b1           (f32)
#define OFF_W     16392     // [256][64]  w = y_pos@k_w1^T                  (f32)
#define OFF_QS    49416     // [256][128] q (scaled)                        (f32)
#define OFF_AX    82184     // [256][128] x @ phi_msg^T                     (f32)
#define OFF_AYP   114952    // [256][128] y @ phi_msg^T - phib              (f32)
#define OFF_GX    147720    // [256][128] x @ g_msg^T                       (f32)
#define OFF_GYP   180488    // [256][128] y @ g_msg^T - gb                  (f32)
#define OFF_PO    213256    // [64 c][4 h][256 q][32]  partial sum(exp*v)   (f32)
#define OFF_PL    2310408   // [64 c][4 h][256 q]      partial sum(exp)     (f32)
#define OFF_WPB   2375944   // [128][64]  bf16 phi_pe @ k_w2
#define OFF_WGB   2380040   // [128][64]  bf16 g_pe @ k_w2
// total < 9.6 MB

// ---------------------------------------------------------------- KA1: U / W (elementwise), 128 blocks
template<bool F32>
__device__ void ka1_body(const void* xpos, const void* ypos,
                         const void* kw1, const void* kb1, float* ws)
{
    int id = blockIdx.x*256 + threadIdx.x;
    if (id < 16384) {
        int n = id >> 6, p = id & 63;
        ws[OFF_U + id] = ldT<F32>(kw1,p*3+0)*ldT<F32>(xpos,n*3+0)
                       + ldT<F32>(kw1,p*3+1)*ldT<F32>(xpos,n*3+1)
                       + ldT<F32>(kw1,p*3+2)*ldT<F32>(xpos,n*3+2) + ldT<F32>(kb1,p);
    } else {
        int i = id - 16384; int m = i >> 6, p = i & 63;
        ws[OFF_W + i] = ldT<F32>(kw1,p*3+0)*ldT<F32>(ypos,m*3+0)
                      + ldT<F32>(kw1,p*3+1)*ldT<F32>(ypos,m*3+1)
                      + ldT<F32>(kw1,p*3+2)*ldT<F32>(ypos,m*3+2);
    }
}
__global__ void __launch_bounds__(256) ka1_elem(
    const void* __restrict__ x, const void* __restrict__ xpos, const void* __restrict__ ypos,
    const void* __restrict__ kw1, const void* __restrict__ kb1, float* __restrict__ ws)
{
    if (detect_f32(x)) ka1_body<true >(xpos, ypos, kw1, kb1, ws);
    else               ka1_body<false>(xpos, ypos, kw1, kb1, ws);
}

// ---------------------------------------------------------------- KA2: WPB / WGB, 64 blocks
template<bool F32>
__device__ void ka2_body(const void* phiw, const void* gw, const void* kw2, float* ws)
{
    int id = blockIdx.x*256 + threadIdx.x;   // 0..16383
    const bool isP = (id < 8192);
    const void* src = isP ? phiw : gw;
    int i = isP ? id : id - 8192;
    int e = i >> 6, p = i & 63;              // e wave-uniform, p = lane -> kw2 coalesced
    float s = 0.f;
    #pragma unroll
    for (int k = 0; k < 16; ++k) {
        short8 a = ldfragT<F32>(src, e*384 + 256 + k*8);
        #pragma unroll
        for (int j = 0; j < 8; ++j)
            s += bs2f(a[j]) * ldT<F32>(kw2, (k*8+j)*64 + p);
    }
    ((short*)(ws + (isP ? OFF_WPB : OFF_WGB)))[i] = f2bs(s);
}
__global__ void __launch_bounds__(256) ka2_wpb(
    const void* __restrict__ x, const void* __restrict__ phiw,
    const void* __restrict__ gw, const void* __restrict__ kw2, float* __restrict__ ws)
{
    if (detect_f32(x)) ka2_body<true >(phiw, gw, kw2, ws);
    else               ka2_body<false>(phiw, gw, kw2, ws);
}

// ---------------------------------------------------------------- KA3: Ax/AyP/Gx/GyP via MFMA, 64 blocks
template<bool F32>
__device__ void ka3_body(const void* x, const void* y, const void* phiw,
                         const void* gw, const void* kb2, float* ws, float* sbias)
{
    const int bi = blockIdx.x, t = threadIdx.x;
    const int w = t >> 6, lane = t & 63, quad = lane >> 4, l16 = lane & 15;
    const int which = bi >> 4, rg = bi & 15;
    const void* am = (which & 1) ? y : x;
    const void* wm = (which < 2) ? phiw : gw;
    if (t < 128) {
        float s = 0.f;
        if (which & 1) {               // bias = pe-part @ k_b2 (folded into AyP/GyP)
            const void* pw = (which == 1) ? phiw : gw;
            #pragma unroll
            for (int k = 0; k < 16; ++k) {
                short8 a  = ldfragT<F32>(pw,  t*384 + 256 + k*8);
                short8 bb = ldfragT<F32>(kb2, k*8);
                #pragma unroll
                for (int j = 0; j < 8; ++j) s += bs2f(a[j]) * bs2f(bb[j]);
            }
        }
        sbias[t] = s;
    }
    __syncthreads();
    const int row0 = rg*16;
    f32x4 acc[2];
    #pragma unroll
    for (int c2 = 0; c2 < 2; ++c2) { acc[c2][0]=0.f; acc[c2][1]=0.f; acc[c2][2]=0.f; acc[c2][3]=0.f; }
    #pragma unroll 2
    for (int k = 0; k < 8; ++k) {
        short8 af = ldfragT<F32>(am, (row0 + l16)*256 + k*32 + quad*8);
        #pragma unroll
        for (int c2 = 0; c2 < 2; ++c2) {
            int ct = w*2 + c2;
            short8 bf = ldfragT<F32>(wm, (ct*16 + l16)*384 + k*32 + quad*8);
            acc[c2] = __builtin_amdgcn_mfma_f32_16x16x32_bf16(af, bf, acc[c2], 0, 0, 0);
        }
    }
    const int base = (which==0) ? OFF_AX : (which==1) ? OFF_AYP : (which==2) ? OFF_GX : OFF_GYP;
    #pragma unroll
    for (int c2 = 0; c2 < 2; ++c2) {
        int col = (w*2+c2)*16 + l16;
        #pragma unroll
        for (int r = 0; r < 4; ++r)
            ws[base + (row0 + quad*4 + r)*128 + col] = acc[c2][r] - sbias[col];
    }
}
__global__ void __launch_bounds__(256) ka3_kproj(
    const void* __restrict__ x, const void* __restrict__ y, const void* __restrict__ phiw,
    const void* __restrict__ gw, const void* __restrict__ kb2, float* __restrict__ ws)
{
    __shared__ float sbias[128];
    if (detect_f32(x)) ka3_body<true >(x, y, phiw, gw, kb2, ws, sbias);
    else               ka3_body<false>(x, y, phiw, gw, kb2, ws, sbias);
}

// ---------------------------------------------------------------- KA4: q = [x|qpe] @ theta^T via MFMA, 16 blocks
template<bool F32>
__device__ void ka4_body(const void* x, const void* xpos, const void* thw,
                         const void* qw1, const void* qb1,
                         const void* qw2, const void* qb2,
                         float* ws, char* smem)
{
    const int t = threadIdx.x;
    const int w = t >> 6, lane = t & 63, quad = lane >> 4, l16 = lane & 15;
    const int row0 = blockIdx.x*16;             // 16 rows per block
    short* qpe_lds = (short*)smem;              // [16][128] bf16 (4 KB)
    short* hq_lds  = (short*)(smem + 4096);     // [16][64]  bf16 (2 KB)
    {   // hq = relu(xpos @ q_w1^T + q_b1)
        int row = t >> 4, p0 = (t & 15)*4;
        float px = ldT<F32>(xpos,(row0+row)*3+0);
        float py = ldT<F32>(xpos,(row0+row)*3+1);
        float pz = ldT<F32>(xpos,(row0+row)*3+2);
        #pragma unroll
        for (int i = 0; i < 4; ++i) {
            int p = p0 + i;
            float v = ldT<F32>(qw1,p*3+0)*px + ldT<F32>(qw1,p*3+1)*py
                    + ldT<F32>(qw1,p*3+2)*pz + ldT<F32>(qb1,p);
            hq_lds[row*64 + p] = f2bs(fmaxf(v, 0.f));
        }
    }
    __syncthreads();
    {   // qpe = hq @ q_w2^T + q_b2 (8 col-tiles over 4 waves)
        const short8 a0 = *(const short8*)(hq_lds + l16*64 + quad*8);
        const short8 a1 = *(const short8*)(hq_lds + l16*64 + 32 + quad*8);
        #pragma unroll
        for (int c2 = 0; c2 < 2; ++c2) {
            int ct = w*2 + c2;
            f32x4 acc; acc[0]=0.f; acc[1]=0.f; acc[2]=0.f; acc[3]=0.f;
            short8 b0 = ldfragT<F32>(qw2, (ct*16+l16)*64 + quad*8);
            short8 b1 = ldfragT<F32>(qw2, (ct*16+l16)*64 + 32 + quad*8);
            acc = __builtin_amdgcn_mfma_f32_16x16x32_bf16(a0, b0, acc, 0, 0, 0);
            acc = __builtin_amdgcn_mfma_f32_16x16x32_bf16(a1, b1, acc, 0, 0, 0);
            float qb = ldT<F32>(qb2, ct*16+l16);
            #pragma unroll
            for (int r = 0; r < 4; ++r)
                qpe_lds[(quad*4 + r)*128 + ct*16 + l16] = f2bs(acc[r] + qb);
        }
    }
    __syncthreads();
    f32x4 acc[2];
    #pragma unroll
    for (int c2 = 0; c2 < 2; ++c2) { acc[c2][0]=0.f; acc[c2][1]=0.f; acc[c2][2]=0.f; acc[c2][3]=0.f; }
    for (int k = 0; k < 12; ++k) {
        const short8 af = (k < 8)
            ? ldfragT<F32>(x, (row0 + l16)*256 + k*32 + quad*8)
            : *(const short8*)(qpe_lds + l16*128 + (k-8)*32 + quad*8);
        #pragma unroll
        for (int c2 = 0; c2 < 2; ++c2) {
            int ct = w*2 + c2;
            short8 bf = ldfragT<F32>(thw, (ct*16+l16)*384 + k*32 + quad*8);
            acc[c2] = __builtin_amdgcn_mfma_f32_16x16x32_bf16(af, bf, acc[c2], 0, 0, 0);
        }
    }
    #pragma unroll
    for (int c2 = 0; c2 < 2; ++c2)
        #pragma unroll
        for (int r = 0; r < 4; ++r)
            ws[OFF_QS + (row0 + quad*4 + r)*128 + (w*2+c2)*16 + l16] =
                acc[c2][r] * 0.17677669529663687f;   // * HD^-0.5
}
__global__ void __launch_bounds__(256) ka4_q(
    const void* __restrict__ x, const void* __restrict__ xpos, const void* __restrict__ thw,
    const void* __restrict__ qw1, const void* __restrict__ qb1,
    const void* __restrict__ qw2, const void* __restrict__ qb2, float* __restrict__ ws)
{
    __shared__ alignas(16) char smem[6144];
    if (detect_f32(x)) ka4_body<true >(x, xpos, thw, qw1, qb1, qw2, qb2, ws, smem);
    else               ka4_body<false>(x, xpos, thw, qw1, qb1, qw2, qb2, ws, smem);
}

// ---------------------------------------------------------------- K3: MFMA k/v build + attention partials
// grid (c=64, h=4, qh=2), 512 threads (8 waves), 2 blocks/CU.
// Scores computed as S^T = K·Q^T with K rows stored in PERMUTED slots so that
// exp(S) lands directly in the PV A-operand registers — no P LDS round-trip.
// Slot map: local key kl (0..31) -> slot ((kl&4)?16:0) + (kl>>3)*4 + (kl&3);
// then attn lane l16 reads slot kc*32+l16 (mf0) / kc*32+16+l16 (mf1), giving
// s0[r]=P[q=l16][k=quad*8+r], s1[r]=P[q=l16][k=quad*8+4+r] == A-frag exactly.
__global__ void __launch_bounds__(512, 4) k3_attn(float* __restrict__ ws)
{
    const int c = blockIdx.x, h = blockIdx.y, qh = blockIdx.z;
    const int tid = threadIdx.x;
    const int w = tid >> 6, lane = tid & 63;
    const int quad = lane >> 4, l16 = lane & 15;

    __shared__ float sW[64];
    __shared__ float sAy[32];
    __shared__ float sGy[32];
    __shared__ alignas(16) short s_hact[256*72];   // 36 KB
    __shared__ alignas(16) short s_k[256*40];      // 20 KB (permuted slots)
    __shared__ alignas(16) short s_vt[32*264];     // 16.5 KB (natural key order)

    const int q0 = qh*128 + w*16;
    short8 qa;   // Q[q=l16][d=quad*8+j] — serves as the B-operand of S^T = K·Q^T
    {
        const float* qp = ws + OFF_QS + (size_t)(q0 + l16)*128 + h*32 + quad*8;
        #pragma unroll
        for (int j = 0; j < 8; ++j) qa[j] = f2bs(qp[j]);
    }

    f32x4 o[2];
    float lpq = 0.f;   // per-lane: sum of exp over this lane's key subset (quad's 8-blocks)
    #pragma unroll
    for (int d = 0; d < 2; ++d) { o[d][0]=0.f; o[d][1]=0.f; o[d][2]=0.f; o[d][3]=0.f; }

    const int which = w & 1, dtb = (w >> 1) & 1, ktg = w >> 2;
    const short* wbm = (const short*)(ws + (which ? OFF_WGB : OFF_WPB));
    const int ecol = h*32 + dtb*16 + l16;
    const short8 wb0 = *(const short8*)(wbm + ecol*64 + quad*8);
    const short8 wb1 = *(const short8*)(wbm + ecol*64 + 32 + quad*8);
    const float* xb = ws + (which ? OFF_GX : OFF_AX);

    for (int mi = 0; mi < 4; ++mi) {
        const int m = c*4 + mi;
        __syncthreads();
        if (tid < 64)       sW[tid]      = ws[OFF_W + m*64 + tid];
        else if (tid < 96)  sAy[tid-64]  = ws[OFF_AYP + m*128 + h*32 + (tid-64)];
        else if (tid < 128) sGy[tid-96]  = ws[OFF_GYP + m*128 + h*32 + (tid-96)];
        __syncthreads();

        {   // hact[key][p] = relu(u[key][p] - w[m][p])
            const int key = tid >> 1, half = tid & 1;
            const float4* up = (const float4*)(ws + OFF_U + key*64 + half*32);
            short* hd = s_hact + key*72 + half*32;
            #pragma unroll
            for (int i = 0; i < 8; ++i) {
                float4 u4 = up[i]; int p = half*32 + i*4;
                hd[i*4+0] = f2bs(fmaxf(u4.x - sW[p+0], 0.f));
                hd[i*4+1] = f2bs(fmaxf(u4.y - sW[p+1], 0.f));
                hd[i*4+2] = f2bs(fmaxf(u4.z - sW[p+2], 0.f));
                hd[i*4+3] = f2bs(fmaxf(u4.w - sW[p+3], 0.f));
            }
        }
        __syncthreads();

        {   // K/V build via MFMA; K stored at permuted slots, V natural-transposed
            const float ycol = (which ? sGy : sAy)[dtb*16 + l16];
            #pragma unroll 2
            for (int i = 0; i < 8; ++i) {
                const int kt = ktg*8 + i;
                f32x4 acc;
                #pragma unroll
                for (int r = 0; r < 4; ++r)
                    acc[r] = xb[(size_t)(kt*16 + quad*4 + r)*128 + ecol] - ycol;
                const short8 a0 = *(const short8*)(s_hact + (kt*16 + l16)*72 + quad*8);
                const short8 a1 = *(const short8*)(s_hact + (kt*16 + l16)*72 + 32 + quad*8);
                acc = __builtin_amdgcn_mfma_f32_16x16x32_bf16(a0, wb0, acc, 0, 0, 0);
                acc = __builtin_amdgcn_mfma_f32_16x16x32_bf16(a1, wb1, acc, 0, 0, 0);
                if (which == 0) {
                    // slot for key kt*16+quad*4+r (kl = (kt&1)*16 + quad*4 + r):
                    //   (kt>>1)*32 + (quad&1)*16 + ((kt&1)*2 + (quad>>1))*4 + r
                    const int slot0 = (kt >> 1)*32 + (quad & 1)*16 + ((kt & 1)*2 + (quad >> 1))*4;
                    #pragma unroll
                    for (int r = 0; r < 4; ++r)
                        s_k[(slot0 + r)*40 + dtb*16 + l16] = f2bs(acc[r]);
                } else {
                    #pragma unroll
                    for (int r = 0; r < 4; ++r)
                        s_vt[(dtb*16 + l16)*264 + kt*16 + quad*4 + r] = f2bs(acc[r]);
                }
            }
        }
        __syncthreads();

        // attention: per 32-key chunk: S^T MFMAs -> exp (registers) -> PV MFMAs
        for (int kc = 0; kc < 8; ++kc) {
            const short8 ka0 = *(const short8*)(s_k + (kc*32 + l16)*40 + quad*8);
            const short8 ka1 = *(const short8*)(s_k + (kc*32 + 16 + l16)*40 + quad*8);
            const short8 vb0 = *(const short8*)(s_vt + l16*264 + kc*32 + quad*8);
            const short8 vb1 = *(const short8*)(s_vt + (16 + l16)*264 + kc*32 + quad*8);
            f32x4 z; z[0]=0.f; z[1]=0.f; z[2]=0.f; z[3]=0.f;
            f32x4 s0 = __builtin_amdgcn_mfma_f32_16x16x32_bf16(ka0, qa, z, 0, 0, 0);
            f32x4 s1 = __builtin_amdgcn_mfma_f32_16x16x32_bf16(ka1, qa, z, 0, 0, 0);
            short8 pfrag;
            #pragma unroll
            for (int r = 0; r < 4; ++r) {
                float e0 = __expf(s0[r]);   // P[q=l16][k=quad*8+r]
                float e1 = __expf(s1[r]);   // P[q=l16][k=quad*8+4+r]
                lpq += e0 + e1;
                pfrag[r]   = f2bs(e0);
                pfrag[r+4] = f2bs(e1);
            }
            o[0] = __builtin_amdgcn_mfma_f32_16x16x32_bf16(pfrag, vb0, o[0], 0, 0, 0);
            o[1] = __builtin_amdgcn_mfma_f32_16x16x32_bf16(pfrag, vb1, o[1], 0, 0, 0);
        }
    }

    #pragma unroll
    for (int dtl = 0; dtl < 2; ++dtl)
        #pragma unroll
        for (int r = 0; r < 4; ++r)
            ws[OFF_PO + (size_t)((c*4 + h)*256 + q0 + quad*4 + r)*32 + dtl*16 + l16] = o[dtl][r];
    {   // lp: sum the 4 quads' partial key-sums for each q=l16
        float v = lpq;
        v += __shfl_xor(v, 16);
        v += __shfl_xor(v, 32);
        if (lane < 16)
            ws[OFF_PL + (c*4 + h)*256 + q0 + lane] = v;
    }
}

// ---------------------------------------------------------------- K4 body (templated on dtype)
template<bool F32>
__device__ void k4_body(
    const float* __restrict__ ws, const void* __restrict__ x,
    const void* __restrict__ outw, const void* __restrict__ lng,
    const void* __restrict__ lnb, void* __restrict__ outp,
    float (*pl4)[256], float* red, float* o2, float* stat)
{
    int q = blockIdx.x, t = threadIdx.x;

    #pragma unroll
    for (int h = 0; h < 4; ++h)
        pl4[h][t] = (t < 64) ? ws[OFF_PL + (t*4 + h)*256 + q] : 0.f;
    __syncthreads();
    for (int s = 128; s > 0; s >>= 1) {
        if (t < s) {
            pl4[0][t] += pl4[0][t+s]; pl4[1][t] += pl4[1][t+s];
            pl4[2][t] += pl4[2][t+s]; pl4[3][t] += pl4[3][t+s];
        }
        __syncthreads();
    }
    int e = t & 127, h2 = e >> 5, d = e & 31, half = t >> 7;
    float a = 0.f;
    #pragma unroll
    for (int mm = 0; mm < 32; ++mm) {
        int c = half*32 + mm;
        a += ws[OFF_PO + ((c*4 + h2)*256 + q)*32 + d];
    }
    red[t] = a;
    __syncthreads();
    if (t < 128) o2[t] = (red[t] + red[t+128]) / pl4[t>>5][0];
    __syncthreads();

    float rv = ldT<F32>(x, q*256 + t);
    #pragma unroll
    for (int i = 0; i < 16; ++i) {
        short8 wv = ldfragT<F32>(outw, t*128 + i*8);
        #pragma unroll
        for (int j = 0; j < 8; ++j) rv += o2[i*8+j]*bs2f(wv[j]);
    }
    red[t] = rv; __syncthreads();
    for (int s = 128; s > 0; s >>= 1) { if (t < s) red[t] += red[t+s]; __syncthreads(); }
    if (t == 0) stat[0] = red[0] * (1.f/256.f);
    __syncthreads();
    float mu = stat[0];
    float dv = rv - mu;
    red[t] = dv*dv; __syncthreads();
    for (int s = 128; s > 0; s >>= 1) { if (t < s) red[t] += red[t+s]; __syncthreads(); }
    if (t == 0) stat[1] = red[0] * (1.f/256.f);
    __syncthreads();
    float rstd = rsqrtf(stat[1] + 1e-5f);
    float val = dv*rstd*ldT<F32>(lng,t) + ldT<F32>(lnb,t);
    if constexpr (F32) ((float*)outp)[q*256 + t] = val;
    else               ((bf16*)outp)[q*256 + t] = __float2bfloat16(val);
}

__global__ void __launch_bounds__(256) k4_out(
    const float* __restrict__ ws, const void* __restrict__ x,
    const void* __restrict__ outw, const void* __restrict__ lng,
    const void* __restrict__ lnb, void* __restrict__ outp)
{
    __shared__ float pl4[4][256];
    __shared__ float red[256];
    __shared__ float o2[128];
    __shared__ float stat[2];
    const bool f32 = detect_f32(x);
    if (f32) k4_body<true >(ws, x, outw, lng, lnb, outp, pl4, red, o2, stat);
    else     k4_body<false>(ws, x, outw, lng, lnb, outp, pl4, red, o2, stat);
}

// ----------------------------------------------------------------
extern "C" void kernel_launch(void* const* d_in, const int* in_sizes, int n_in,
                              void* d_out, int out_size, void* d_ws, size_t ws_size,
                              hipStream_t stream)
{
    const void* x    = d_in[0];
    const void* y    = d_in[1];
    const void* xpos = d_in[2];
    const void* ypos = d_in[3];
    const void* thw  = d_in[4];
    const void* phiw = d_in[5];
    const void* gw   = d_in[6];
    const void* qw1  = d_in[7];
    const void* qb1  = d_in[8];
    const void* qw2  = d_in[9];
    const void* qb2  = d_in[10];
    const void* kw1  = d_in[11];
    const void* kb1  = d_in[12];
    const void* kw2  = d_in[13];
    const void* kb2  = d_in[14];
    const void* outw = d_in[15];
    const void* lng  = d_in[16];
    const void* lnb  = d_in[17];
    float* ws = (float*)d_ws;

    ka1_elem<<<128, 256, 0, stream>>>(x, xpos, ypos, kw1, kb1, ws);
    ka2_wpb<<<64, 256, 0, stream>>>(x, phiw, gw, kw2, ws);
    ka3_kproj<<<64, 256, 0, stream>>>(x, y, phiw, gw, kb2, ws);
    ka4_q<<<16, 256, 0, stream>>>(x, xpos, thw, qw1, qb1, qw2, qb2, ws);
    k3_attn<<<dim3(64, 4, 2), 512, 0, stream>>>(ws);
    k4_out<<<256, 256, 0, stream>>>(ws, x, outw, lng, lnb, d_out);
}